// Round 12
// baseline (1019.539 us; speedup 1.0000x reference)
//
#include <hip/hip_runtime.h>
#include <hip/hip_bf16.h>
#include <cstdint>
#include <cstddef>

typedef __bf16 bf16_t;
typedef __bf16 bf16x8 __attribute__((ext_vector_type(8)));
typedef __bf16 bf16x4 __attribute__((ext_vector_type(4)));
typedef float f32x4 __attribute__((ext_vector_type(4)));

#define NN 20000
#define NE 320000
#define FIN 5189
#define KP1 5216   // FIN padded to mult of 32
#define NORIG 183

__device__ inline f32x4 ld4u(const float* p) {
  f32x4 v; __builtin_memcpy(&v, p, 16); return v;
}

__device__ inline void gload_lds16(const bf16_t* g, bf16_t* l) {
  __builtin_amdgcn_global_load_lds(
      (const __attribute__((address_space(1))) uint32_t*)g,
      (__attribute__((address_space(3))) uint32_t*)l, 16, 0, 0);
}

// k-slot swizzle (proven r3-r8): spreads row-starts across banks, 2-way max
__device__ inline int swz(int r) { return (r ^ (r >> 2)) & 3; }

// ---------------------------------------------------------------------------
// x (fp32 [NN][FIN]) -> xb (bf16 [NN][KP1], zero-padded cols)
// ---------------------------------------------------------------------------
__global__ void k_cvtpad(const float* __restrict__ x, bf16_t* __restrict__ xb) {
  const int total = NN * (KP1 / 8);
  for (int idx = blockIdx.x * 256 + threadIdx.x; idx < total; idx += gridDim.x * 256) {
    int row = idx / (KP1 / 8);
    int c8  = idx - row * (KP1 / 8);
    int col = c8 * 8;
    bf16x8 v{};
    const float* xp = x + (size_t)row * FIN + col;
    if (col + 8 <= FIN) {
      f32x4 a = ld4u(xp), b = ld4u(xp + 4);
#pragma unroll
      for (int j = 0; j < 4; ++j) { v[j] = (bf16_t)a[j]; v[4 + j] = (bf16_t)b[j]; }
    } else {
#pragma unroll
      for (int j = 0; j < 8; ++j) v[j] = (col + j < FIN) ? (bf16_t)xp[j] : (bf16_t)0.f;
    }
    *(bf16x8*)&xb[(size_t)row * KP1 + col] = v;
  }
}

// ---------------------------------------------------------------------------
// Unified GEMM (proven r4 2-phase, 128x128 tile, BK=32, 256 threads 2x2 waves)
// + T1 bijective XCD-chunk swizzle (flat 1-D grid, NBX col-blocks)
// + optional dinv epilogue: C[row,col] = bf16(acc * dscale[(col>>8)*NN+row])
// ---------------------------------------------------------------------------
__global__ __launch_bounds__(256) void k_gemm_s(
    const bf16_t* __restrict__ A, const bf16_t* __restrict__ Bt,
    bf16_t* __restrict__ C, const float* __restrict__ bias,
    const float* __restrict__ dscale,
    int M, int N, int Kp, int relu, int NBX)
{
  __shared__ __align__(16) bf16_t As[2][128 * 32];
  __shared__ __align__(16) bf16_t Bs[2][128 * 32];
  // bijective XCD-chunk decode (m204)
  const int nwg = gridDim.x;
  const int q = nwg >> 3, rr = nwg & 7;
  const int xcd = blockIdx.x & 7, jj = blockIdx.x >> 3;
  const int L = (xcd < rr ? xcd * (q + 1) : rr * (q + 1) + (xcd - rr) * q) + jj;
  const int bx = L % NBX, by = L / NBX;

  const int tid = threadIdx.x, lane = tid & 63, wave = tid >> 6;
  const int m0 = by * 128, n0 = bx * 128;
  const int wr = (wave >> 1) * 64, wc = (wave & 1) * 64;
  const int fm = lane & 15, fs = lane >> 4;

  const int r0 = tid >> 2, r1 = 64 + r0, sl = tid & 3;
  int ag0 = m0 + r0; if (ag0 >= M) ag0 = M - 1;
  int ag1 = m0 + r1; if (ag1 >= M) ag1 = M - 1;
  const bf16_t* asrc0 = A + (size_t)ag0 * Kp + (sl ^ swz(r0)) * 8;
  const bf16_t* asrc1 = A + (size_t)ag1 * Kp + (sl ^ swz(r1)) * 8;
  const bf16_t* bsrc0 = Bt + (size_t)(n0 + r0) * Kp + (sl ^ swz(r0)) * 8;
  const bf16_t* bsrc1 = Bt + (size_t)(n0 + r1) * Kp + (sl ^ swz(r1)) * 8;

  bf16_t* adst0 = &As[0][0] + wave * 512;
  bf16_t* adst1 = &As[0][0] + 2048 + wave * 512;
  bf16_t* bdst0 = &Bs[0][0] + wave * 512;
  bf16_t* bdst1 = &Bs[0][0] + 2048 + wave * 512;

  int aoff[4], boff[4];
#pragma unroll
  for (int i = 0; i < 4; ++i) {
    int ra = wr + i * 16 + fm;
    aoff[i] = ra * 32 + (fs ^ swz(ra)) * 8;
    int rb = wc + i * 16 + fm;
    boff[i] = rb * 32 + (fs ^ swz(rb)) * 8;
  }

  f32x4 acc[4][4];
#pragma unroll
  for (int i = 0; i < 4; ++i)
#pragma unroll
    for (int j = 0; j < 4; ++j) acc[i][j] = {0.f, 0.f, 0.f, 0.f};

#define STAGES(buf, kof) do { \
    gload_lds16(asrc0 + (kof), adst0 + (buf) * (128 * 32)); \
    gload_lds16(asrc1 + (kof), adst1 + (buf) * (128 * 32)); \
    gload_lds16(bsrc0 + (kof), bdst0 + (buf) * (128 * 32)); \
    gload_lds16(bsrc1 + (kof), bdst1 + (buf) * (128 * 32)); \
  } while (0)

  const int NT = Kp / 32;
  STAGES(0, 0);
  __syncthreads();
  int buf = 0;
  for (int t = 0; t < NT - 1; ++t) {
    STAGES(buf ^ 1, (t + 1) * 32);
    bf16x8 af[4], bfv[4];
#pragma unroll
    for (int i = 0; i < 4; ++i) af[i] = *(const bf16x8*)&As[buf][aoff[i]];
#pragma unroll
    for (int j = 0; j < 4; ++j) bfv[j] = *(const bf16x8*)&Bs[buf][boff[j]];
#pragma unroll
    for (int i = 0; i < 4; ++i)
#pragma unroll
      for (int j = 0; j < 4; ++j)
        acc[i][j] = __builtin_amdgcn_mfma_f32_16x16x32_bf16(af[i], bfv[j], acc[i][j], 0, 0, 0);
    __syncthreads();
    buf ^= 1;
  }
  {
    bf16x8 af[4], bfv[4];
#pragma unroll
    for (int i = 0; i < 4; ++i) af[i] = *(const bf16x8*)&As[buf][aoff[i]];
#pragma unroll
    for (int j = 0; j < 4; ++j) bfv[j] = *(const bf16x8*)&Bs[buf][boff[j]];
#pragma unroll
    for (int i = 0; i < 4; ++i)
#pragma unroll
      for (int j = 0; j < 4; ++j)
        acc[i][j] = __builtin_amdgcn_mfma_f32_16x16x32_bf16(af[i], bfv[j], acc[i][j], 0, 0, 0);
  }

  const int ccol = n0 + wc + fm;
  const int rrel = (n0 + wc) >> 8;   // relation block (uniform per wave)
  const float* dsp = dscale ? dscale + (size_t)rrel * NN : nullptr;
#pragma unroll
  for (int i = 0; i < 4; ++i) {
    const int rb2 = m0 + wr + i * 16 + (lane >> 4) * 4;
#pragma unroll
    for (int r = 0; r < 4; ++r) {
      const int row = rb2 + r;
      if (row < M) {
        bf16_t* cp = C + (size_t)row * N + ccol;
        const float sc = dsp ? dsp[row] : 1.f;
#pragma unroll
        for (int j = 0; j < 4; ++j) {
          float v = acc[i][j][r];
          if (bias) v += bias[ccol + j * 16];
          if (relu) v = fmaxf(v, 0.f);
          cp[j * 16] = (bf16_t)(v * sc);
        }
      }
    }
  }
}

// ---------------------------------------------------------------------------
// Weight transpose+convert: src = G stacked [K][256] fp32 -> dst[G*256][Kp] bf16
// ---------------------------------------------------------------------------
__global__ void k_transw(const float* __restrict__ src, bf16_t* __restrict__ dst,
                         int K, int Kp)
{
  __shared__ float tile[32][33];
  const int g = blockIdx.z;
  const int k0 = blockIdx.x * 32, j0 = blockIdx.y * 32;
  const int tx = threadIdx.x, ty = threadIdx.y;  // 32 x 8
  const float* sp = src + (size_t)g * K * 256;
#pragma unroll
  for (int i = 0; i < 4; ++i) {
    int k = k0 + ty + i * 8;
    tile[ty + i * 8][tx] = (k < K) ? sp[(size_t)k * 256 + j0 + tx] : 0.f;
  }
  __syncthreads();
  bf16_t* dp = dst + (size_t)g * 256 * Kp;
#pragma unroll
  for (int i = 0; i < 4; ++i) {
    int n = j0 + ty + i * 8;
    dp[(size_t)n * Kp + k0 + tx] = (bf16_t)tile[tx][ty + i * 8];
  }
}

// ---------------------------------------------------------------------------
// CSR build — merged launches.
// ---------------------------------------------------------------------------
__global__ void k_deg3(const int* __restrict__ e1, const int* __restrict__ e2,
                       const int* __restrict__ e3, int* __restrict__ deg) {
  int i = blockIdx.x * 256 + threadIdx.x;
  if (i >= 3 * NE) return;
  int r = i / NE, e = i - r * NE;
  const int* d = (r == 0 ? e1 : (r == 1 ? e2 : e3)) + NE;
  atomicAdd(&deg[r * NN + d[e]], 1);
}

__global__ void k_degi(const int* __restrict__ i1, const int* __restrict__ i3,
                       int* __restrict__ deg183) {
  int i = blockIdx.x * 256 + threadIdx.x;
  if (i >= 2 * NN) return;
  int r = i / NN, v = i - r * NN;
  int g = (r ? i3 : i1)[v];
  atomicAdd(&deg183[r * NORIG + g], 1);
}

__global__ void k_dinv(const int* __restrict__ deg, float* __restrict__ dinv) {
  int v = blockIdx.x * 256 + threadIdx.x;
  if (v < 3 * NN) dinv[v] = rsqrtf((float)(deg[v] + 1));
}

#define SCAN_T 1024
#define SCAN_CH 20
__global__ __launch_bounds__(SCAN_T) void k_scan(
    const int* __restrict__ deg, int* __restrict__ rp, int* __restrict__ cur)
{
  const int r = blockIdx.x;
  const int* d = deg + r * NN;
  int* rpr = rp + r * (NN + 1);
  int* cr  = cur + r * NN;
  __shared__ int ts[SCAN_T];
  const int t = threadIdx.x;
  const int base = t * SCAN_CH;
  int local[SCAN_CH];
  int sum = 0;
#pragma unroll
  for (int i = 0; i < SCAN_CH; ++i) {
    int v = base + i;
    int x = (v < NN) ? d[v] : 0;
    local[i] = sum; sum += x;
  }
  ts[t] = sum; __syncthreads();
  for (int ofs = 1; ofs < SCAN_T; ofs <<= 1) {
    int v = ts[t];
    int w = (t >= ofs) ? ts[t - ofs] : 0;
    __syncthreads();
    ts[t] = v + w;
    __syncthreads();
  }
  int excl = (t == 0) ? 0 : ts[t - 1];
#pragma unroll
  for (int i = 0; i < SCAN_CH; ++i) {
    int v = base + i;
    if (v < NN) { int val = excl + local[i]; rpr[v] = val; cr[v] = val; }
  }
  if (t == SCAN_T - 1) rpr[NN] = ts[SCAN_T - 1];
}

__global__ void k_scan183(const int* __restrict__ deg183, int* __restrict__ rpg,
                          int* __restrict__ cur183) {
  const int r = blockIdx.x;
  const int* d = deg183 + r * NORIG;
  int* rpr = rpg + r * (NORIG + 1);
  int* cr  = cur183 + r * NORIG;
  __shared__ int ts[256];
  const int t = threadIdx.x;
  int x = (t < NORIG) ? d[t] : 0;
  ts[t] = x; __syncthreads();
  for (int o = 1; o < 256; o <<= 1) {
    int v = ts[t];
    int w = (t >= o) ? ts[t - o] : 0;
    __syncthreads();
    ts[t] = v + w;
    __syncthreads();
  }
  if (t < NORIG) {
    int excl = ts[t] - x;
    rpr[t] = excl; cr[t] = excl;
    if (t == NORIG - 1) rpr[NORIG] = ts[t];
  }
}

__global__ void k_bucket3(const int* __restrict__ e1, const int* __restrict__ e2,
                          const int* __restrict__ e3, int* __restrict__ cur,
                          int* __restrict__ col) {
  int i = blockIdx.x * 256 + threadIdx.x;
  if (i >= 3 * NE) return;
  int r = i / NE, e = i - r * NE;
  const int* ei = (r == 0 ? e1 : (r == 1 ? e2 : e3));
  int d = ei[NE + e];
  int pos = atomicAdd(&cur[r * NN + d], 1);
  col[(size_t)r * NE + pos] = ei[e];
}

__global__ void k_bucketi(const int* __restrict__ i1, const int* __restrict__ i3,
                          int* __restrict__ cur183, int* __restrict__ colg) {
  int i = blockIdx.x * 256 + threadIdx.x;
  if (i >= 2 * NN) return;
  int r = i / NN, v = i - r * NN;
  int g = (r ? i3 : i1)[v];
  int pos = atomicAdd(&cur183[r * NORIG + g], 1);
  colg[r * NN + pos] = v;
}

// ---------------------------------------------------------------------------
// Fused GCN aggregation over PRE-SCALED P (P = H*dinv from GEMM epilogue):
// Out[v] = relu(dv * (P[v] + sum_{s in N(v)} P[s]) + bias), bf16 in/out.
// One wave per (vertex, relation); 16-deep load pipeline.
// ---------------------------------------------------------------------------
__global__ __launch_bounds__(256) void k_gatherb(
    const bf16_t* __restrict__ P, bf16_t* __restrict__ Out,
    const int* __restrict__ rp, const int* __restrict__ col,
    const float* __restrict__ dinv, const float* __restrict__ bias)
{
  const int wv = threadIdx.x >> 6, lane = threadIdx.x & 63;
  const int v = blockIdx.x * 4 + wv;
  const int r = blockIdx.y;
  const int roff = r << 8;
  const int* rpr = rp + r * (NN + 1);
  const int* cr  = col + (size_t)r * NE;
  const float dv = dinv[r * NN + v];
  const int c0 = roff + lane * 4;

  bf16x4 hs = *(const bf16x4*)&P[(size_t)v * 768 + c0];
  float a0 = (float)hs[0], a1 = (float)hs[1], a2 = (float)hs[2], a3 = (float)hs[3];

  int i = rpr[v];
  const int e = rpr[v + 1];
  for (; i + 16 <= e; i += 16) {
    bf16x4 h[16];
#pragma unroll
    for (int u = 0; u < 16; ++u) {
      int s = cr[i + u];
      h[u] = *(const bf16x4*)&P[(size_t)s * 768 + c0];
    }
#pragma unroll
    for (int u = 0; u < 16; ++u) {
      a0 += (float)h[u][0]; a1 += (float)h[u][1];
      a2 += (float)h[u][2]; a3 += (float)h[u][3];
    }
  }
  for (; i + 4 <= e; i += 4) {
    bf16x4 h[4];
#pragma unroll
    for (int u = 0; u < 4; ++u) {
      int s = cr[i + u];
      h[u] = *(const bf16x4*)&P[(size_t)s * 768 + c0];
    }
#pragma unroll
    for (int u = 0; u < 4; ++u) {
      a0 += (float)h[u][0]; a1 += (float)h[u][1];
      a2 += (float)h[u][2]; a3 += (float)h[u][3];
    }
  }
  for (; i < e; ++i) {
    int s = cr[i];
    bf16x4 h = *(const bf16x4*)&P[(size_t)s * 768 + c0];
    a0 += (float)h[0]; a1 += (float)h[1];
    a2 += (float)h[2]; a3 += (float)h[3];
  }
  f32x4 bb = ld4u(bias + c0);
  bf16x4 o;
  o[0] = (bf16_t)fmaxf(dv * a0 + bb[0], 0.f);
  o[1] = (bf16_t)fmaxf(dv * a1 + bb[1], 0.f);
  o[2] = (bf16_t)fmaxf(dv * a2 + bb[2], 0.f);
  o[3] = (bf16_t)fmaxf(dv * a3 + bb[3], 0.f);
  *(bf16x4*)&Out[(size_t)v * 768 + c0] = o;
}

// ---------------------------------------------------------------------------
// Readout: group means via index-CSR (no atomics) + MLP + log_softmax.
// ---------------------------------------------------------------------------
__global__ __launch_bounds__(256) void k_final2(
    const bf16_t* __restrict__ h2,
    const int* __restrict__ rpg, const int* __restrict__ colg,
    const float* __restrict__ mw1, const float* __restrict__ mb1,
    const float* __restrict__ mw2, const float* __restrict__ mb2,
    float* __restrict__ out)
{
  __shared__ float xc[768];
  __shared__ float tt[256];
  __shared__ float lg[8];
  const int g = blockIdx.x, tid = threadIdx.x;
  const int* rp1 = rpg;
  const int* rp3 = rpg + (NORIG + 1);
  const int* c1v = colg;
  const int* c3v = colg + NN;

  float a1 = 0.f;
  int b1 = rp1[g], e1 = rp1[g + 1];
  for (int i = b1; i < e1; ++i) a1 += (float)h2[(size_t)c1v[i] * 256 + tid];
  float a3 = 0.f;
  int b3 = rp3[g], e3 = rp3[g + 1];
  for (int i = b3; i < e3; ++i) a3 += (float)h2[(size_t)c3v[i] * 256 + tid];
  a1 *= 1.f / fmaxf((float)(e1 - b1), 1.f);
  a3 *= 1.f / fmaxf((float)(e3 - b3), 1.f);
  xc[tid] = a1;
  xc[256 + tid] = a3;
  xc[512 + tid] = a3;
  __syncthreads();
  float acc = mb1[tid];
  for (int k = 0; k < 768; ++k) acc += xc[k] * mw1[k * 256 + tid];
  tt[tid] = fmaxf(acc, 0.f);
  __syncthreads();
  if (tid < 7) {
    float a = mb2[tid];
    for (int k = 0; k < 256; ++k) a += tt[k] * mw2[k * 7 + tid];
    lg[tid] = a;
  }
  __syncthreads();
  if (tid == 0) {
    float mx = lg[0];
    for (int c2 = 1; c2 < 7; ++c2) mx = fmaxf(mx, lg[c2]);
    float sum = 0.f;
    for (int c2 = 0; c2 < 7; ++c2) sum += expf(lg[c2] - mx);
    float lse = logf(sum) + mx;
    for (int c2 = 0; c2 < 7; ++c2) out[g * 7 + c2] = lg[c2] - lse;
  }
}

// ---------------------------------------------------------------------------
extern "C" void kernel_launch(void* const* d_in, const int* in_sizes, int n_in,
                              void* d_out, int out_size, void* d_ws, size_t ws_size,
                              hipStream_t stream) {
  const float* x    = (const float*)d_in[0];
  const float* w1   = (const float*)d_in[1];
  const float* b1   = (const float*)d_in[2];
  const float* w2   = (const float*)d_in[3];
  const float* b2   = (const float*)d_in[4];
  const float* m1w1 = (const float*)d_in[5];
  const float* m1b1 = (const float*)d_in[6];
  const float* m1w2 = (const float*)d_in[7];
  const float* m1b2 = (const float*)d_in[8];
  const float* m2w1 = (const float*)d_in[9];
  const float* m2b1 = (const float*)d_in[10];
  const float* m2w2 = (const float*)d_in[11];
  const float* m2b2 = (const float*)d_in[12];
  const float* mw1  = (const float*)d_in[13];
  const float* mb1  = (const float*)d_in[14];
  const float* mw2  = (const float*)d_in[15];
  const float* mb2  = (const float*)d_in[16];
  const int* e1 = (const int*)d_in[17];
  const int* e2 = (const int*)d_in[18];
  const int* e3 = (const int*)d_in[19];
  const int* i1 = (const int*)d_in[20];
  const int* i3 = (const int*)d_in[22];  // index_2 dead in reference (source bug)
  float* out = (float*)d_out;

  char* ws = (char*)d_ws;
  size_t off = 0;
  auto alloc = [&](size_t bytes) {
    char* p = ws + off;
    off += (bytes + 255) & ~(size_t)255;
    return (void*)p;
  };
  bf16_t* xb   = (bf16_t*)alloc((size_t)NN * KP1 * 2);  // 208.6 MB
  bf16_t* wt   = (bf16_t*)alloc((size_t)768 * KP1 * 2); // 8 MB
  bf16_t* a1   = (bf16_t*)alloc((size_t)NN * 768 * 2);
  bf16_t* g1   = (bf16_t*)alloc((size_t)NN * 768 * 2);
  bf16_t* t1   = (bf16_t*)alloc((size_t)NN * 256 * 2);
  bf16_t* h1   = (bf16_t*)alloc((size_t)NN * 256 * 2);
  int*    deg  = (int*)alloc(((size_t)3 * NN + 2 * NORIG) * 4);
  float*  dinv = (float*)alloc((size_t)3 * NN * 4);
  int*    rp   = (int*)alloc((size_t)3 * (NN + 1) * 4);
  int*    cur  = (int*)alloc((size_t)3 * NN * 4);
  int*    col  = (int*)alloc((size_t)3 * NE * 4);
  int*    rpg  = (int*)alloc((size_t)2 * (NORIG + 1) * 4);
  int*    cur183 = (int*)alloc((size_t)2 * NORIG * 4);
  int*    colg = (int*)alloc((size_t)2 * NN * 4);
  int*    deg183 = deg + 3 * NN;

  // ---- CSR build (edges + readout indices) + dinv
  hipMemsetAsync(deg, 0, ((size_t)3 * NN + 2 * NORIG) * 4, stream);
  k_deg3<<<(3 * NE + 255) / 256, 256, 0, stream>>>(e1, e2, e3, deg);
  k_degi<<<(2 * NN + 255) / 256, 256, 0, stream>>>(i1, i3, deg183);
  k_dinv<<<(3 * NN + 255) / 256, 256, 0, stream>>>(deg, dinv);
  k_scan<<<3, SCAN_T, 0, stream>>>(deg, rp, cur);
  k_scan183<<<2, 256, 0, stream>>>(deg183, rpg, cur183);
  k_bucket3<<<(3 * NE + 255) / 256, 256, 0, stream>>>(e1, e2, e3, cur, col);
  k_bucketi<<<(2 * NN + 255) / 256, 256, 0, stream>>>(i1, i3, cur183, colg);

  auto transw = [&](const float* Wsrc, int G, int K, int Kp) {
    k_transw<<<dim3(Kp / 32, 8, G), dim3(32, 8), 0, stream>>>(Wsrc, wt, K, Kp);
  };

  dim3 ggat(NN / 4, 3);
  const int G768 = 6 * 157;  // N=768 GEMMs: NBX=6, NBY=157 (942 blocks)
  const int G256 = 2 * 157;  // N=256 GEMMs: NBX=2, NBY=157 (314 blocks)

  // ---- layer 1 (GEMM writes pre-scaled P = H*dinv for the gather)
  transw(w1, 3, FIN, KP1);
  k_cvtpad<<<2048, 256, 0, stream>>>(x, xb);
  k_gemm_s<<<G768, 256, 0, stream>>>(xb, wt, a1, nullptr, dinv, NN, 768, KP1, 0, 6);
  k_gatherb<<<ggat, 256, 0, stream>>>(a1, g1, rp, col, dinv, b1);
  transw(m1w1, 1, 768, 768);
  k_gemm_s<<<G256, 256, 0, stream>>>(g1, wt, t1, m1b1, nullptr, NN, 256, 768, 1, 2);
  transw(m1w2, 1, 256, 256);
  k_gemm_s<<<G256, 256, 0, stream>>>(t1, wt, h1, m1b2, nullptr, NN, 256, 256, 0, 2);

  // ---- layer 2
  transw(w2, 3, 256, 256);
  k_gemm_s<<<G768, 256, 0, stream>>>(h1, wt, a1, nullptr, dinv, NN, 768, 256, 0, 6);
  k_gatherb<<<ggat, 256, 0, stream>>>(a1, g1, rp, col, dinv, b2);
  transw(m2w1, 1, 768, 768);
  k_gemm_s<<<G256, 256, 0, stream>>>(g1, wt, t1, m2b1, nullptr, NN, 256, 768, 1, 2);
  transw(m2w2, 1, 256, 256);
  k_gemm_s<<<G256, 256, 0, stream>>>(t1, wt, h1, m2b2, nullptr, NN, 256, 256, 0, 2);

  // ---- readout (atomic-free)
  k_final2<<<NORIG, 256, 0, stream>>>(h1, rpg, colg, mw1, mb1, mw2, mb2, out);
}

// Round 13
// 885.370 us; speedup vs baseline: 1.1515x; 1.1515x over previous
//
#include <hip/hip_runtime.h>
#include <hip/hip_bf16.h>
#include <cstdint>
#include <cstddef>

typedef __bf16 bf16_t;
typedef __bf16 bf16x8 __attribute__((ext_vector_type(8)));
typedef __bf16 bf16x4 __attribute__((ext_vector_type(4)));
typedef float f32x4 __attribute__((ext_vector_type(4)));

#define NN 20000
#define NE 320000
#define FIN 5189
#define KP1 5216   // FIN padded to mult of 32
#define NORIG 183

__device__ inline f32x4 ld4u(const float* p) {
  f32x4 v; __builtin_memcpy(&v, p, 16); return v;
}

__device__ inline void gload_lds16(const bf16_t* g, bf16_t* l) {
  __builtin_amdgcn_global_load_lds(
      (const __attribute__((address_space(1))) uint32_t*)g,
      (__attribute__((address_space(3))) uint32_t*)l, 16, 0, 0);
}

// k-slot swizzle (proven r3-r8): spreads row-starts across banks, 2-way max
__device__ inline int swz(int r) { return (r ^ (r >> 2)) & 3; }

// ---------------------------------------------------------------------------
// x (fp32 [NN][FIN]) -> xb (bf16 [NN][KP1], zero-padded cols)
// ---------------------------------------------------------------------------
__global__ void k_cvtpad(const float* __restrict__ x, bf16_t* __restrict__ xb) {
  const int total = NN * (KP1 / 8);
  for (int idx = blockIdx.x * 256 + threadIdx.x; idx < total; idx += gridDim.x * 256) {
    int row = idx / (KP1 / 8);
    int c8  = idx - row * (KP1 / 8);
    int col = c8 * 8;
    bf16x8 v{};
    const float* xp = x + (size_t)row * FIN + col;
    if (col + 8 <= FIN) {
      f32x4 a = ld4u(xp), b = ld4u(xp + 4);
#pragma unroll
      for (int j = 0; j < 4; ++j) { v[j] = (bf16_t)a[j]; v[4 + j] = (bf16_t)b[j]; }
    } else {
#pragma unroll
      for (int j = 0; j < 8; ++j) v[j] = (col + j < FIN) ? (bf16_t)xp[j] : (bf16_t)0.f;
    }
    *(bf16x8*)&xb[(size_t)row * KP1 + col] = v;
  }
}

// ---------------------------------------------------------------------------
// Wide GEMM (proven r4/r6/r8 2-phase) + T1 XCD swizzle + optional dinv epilogue:
// if dscale != nullptr, C[row, col] = bf16(acc * dscale[(col>>8)*NN + row])
// (pre-scaled P for the gather). BM=128 BN=256 BK=32, 512 threads.
// ---------------------------------------------------------------------------
__global__ __launch_bounds__(512) void k_gemm_w(
    const bf16_t* __restrict__ A, const bf16_t* __restrict__ Bt,
    bf16_t* __restrict__ C, const float* __restrict__ bias,
    const float* __restrict__ dscale,
    int M, int N, int Kp, int relu, int NBX)
{
  __shared__ __align__(16) bf16_t As[2][128 * 32];
  __shared__ __align__(16) bf16_t Bs[2][256 * 32];
  // bijective XCD-chunk decode
  const int nwg = gridDim.x;
  const int q = nwg >> 3, rr = nwg & 7;
  const int xcd = blockIdx.x & 7, jj = blockIdx.x >> 3;
  const int L = (xcd < rr ? xcd * (q + 1) : rr * (q + 1) + (xcd - rr) * q) + jj;
  const int bx = L % NBX, by = L / NBX;

  const int tid = threadIdx.x, lane = tid & 63, wave = tid >> 6;
  const int m0 = by * 128, n0 = bx * 256;
  const int wr = (wave >> 2) * 64, wc = (wave & 3) * 64;
  const int fm = lane & 15, fs = lane >> 4;

  const int arow = tid >> 2, asl = tid & 3;
  const int aks = asl ^ swz(arow);
  int agrow = m0 + arow; if (agrow >= M) agrow = M - 1;
  const bf16_t* asrc = A + (size_t)agrow * Kp + aks * 8;

  const int br0 = tid >> 2, br1 = 128 + br0;
  const bf16_t* bsrc0 = Bt + (size_t)(n0 + br0) * Kp + (asl ^ swz(br0)) * 8;
  const bf16_t* bsrc1 = Bt + (size_t)(n0 + br1) * Kp + (asl ^ swz(br1)) * 8;

  bf16_t* adst  = &As[0][0] + wave * 512;
  bf16_t* bdst0 = &Bs[0][0] + wave * 512;
  bf16_t* bdst1 = &Bs[0][0] + 4096 + wave * 512;

  int aoff[4], boff[4];
#pragma unroll
  for (int i = 0; i < 4; ++i) {
    int ra = wr + i * 16 + fm;
    aoff[i] = ra * 32 + (fs ^ swz(ra)) * 8;
    int rb = wc + i * 16 + fm;
    boff[i] = rb * 32 + (fs ^ swz(rb)) * 8;
  }

  f32x4 acc[4][4];
#pragma unroll
  for (int i = 0; i < 4; ++i)
#pragma unroll
    for (int j = 0; j < 4; ++j) acc[i][j] = {0.f, 0.f, 0.f, 0.f};

#define STAGEW(buf, kof) do { \
    gload_lds16(asrc + (kof),  adst  + (buf) * (128 * 32)); \
    gload_lds16(bsrc0 + (kof), bdst0 + (buf) * (256 * 32)); \
    gload_lds16(bsrc1 + (kof), bdst1 + (buf) * (256 * 32)); \
  } while (0)

  const int NT = Kp / 32;
  STAGEW(0, 0);
  __syncthreads();
  int buf = 0;
  for (int t = 0; t < NT - 1; ++t) {
    STAGEW(buf ^ 1, (t + 1) * 32);
    bf16x8 af[4], bfv[4];
#pragma unroll
    for (int i = 0; i < 4; ++i) af[i] = *(const bf16x8*)&As[buf][aoff[i]];
#pragma unroll
    for (int j = 0; j < 4; ++j) bfv[j] = *(const bf16x8*)&Bs[buf][boff[j]];
#pragma unroll
    for (int i = 0; i < 4; ++i)
#pragma unroll
      for (int j = 0; j < 4; ++j)
        acc[i][j] = __builtin_amdgcn_mfma_f32_16x16x32_bf16(af[i], bfv[j], acc[i][j], 0, 0, 0);
    __syncthreads();
    buf ^= 1;
  }
  {
    bf16x8 af[4], bfv[4];
#pragma unroll
    for (int i = 0; i < 4; ++i) af[i] = *(const bf16x8*)&As[buf][aoff[i]];
#pragma unroll
    for (int j = 0; j < 4; ++j) bfv[j] = *(const bf16x8*)&Bs[buf][boff[j]];
#pragma unroll
    for (int i = 0; i < 4; ++i)
#pragma unroll
      for (int j = 0; j < 4; ++j)
        acc[i][j] = __builtin_amdgcn_mfma_f32_16x16x32_bf16(af[i], bfv[j], acc[i][j], 0, 0, 0);
  }

  const int ccol = n0 + wc + fm;
  const int rrel = (n0 + wc) >> 8;   // relation block (uniform per wave)
  const float* dsp = dscale ? dscale + (size_t)rrel * NN : nullptr;
#pragma unroll
  for (int i = 0; i < 4; ++i) {
    const int rb2 = m0 + wr + i * 16 + (lane >> 4) * 4;
#pragma unroll
    for (int r = 0; r < 4; ++r) {
      const int row = rb2 + r;
      if (row < M) {
        bf16_t* cp = C + (size_t)row * N + ccol;
        const float sc = dsp ? dsp[row] : 1.f;
#pragma unroll
        for (int j = 0; j < 4; ++j) {
          float v = acc[i][j][r];
          if (bias) v += bias[ccol + j * 16];
          if (relu) v = fmaxf(v, 0.f);
          cp[j * 16] = (bf16_t)(v * sc);
        }
      }
    }
  }
}

// ---------------------------------------------------------------------------
// Small GEMM (proven r4): BM=128 BN=128 BK=32, 256 threads, 2-phase dbuf.
// ---------------------------------------------------------------------------
__global__ __launch_bounds__(256) void k_gemm_s(
    const bf16_t* __restrict__ A, const bf16_t* __restrict__ Bt,
    bf16_t* __restrict__ C, const float* __restrict__ bias,
    int M, int N, int Kp, int relu)
{
  __shared__ __align__(16) bf16_t As[2][128 * 32];
  __shared__ __align__(16) bf16_t Bs[2][128 * 32];
  const int tid = threadIdx.x, lane = tid & 63, wave = tid >> 6;
  const int m0 = blockIdx.y * 128, n0 = blockIdx.x * 128;
  const int wr = (wave >> 1) * 64, wc = (wave & 1) * 64;
  const int fm = lane & 15, fs = lane >> 4;

  const int r0 = tid >> 2, r1 = 64 + r0, sl = tid & 3;
  int ag0 = m0 + r0; if (ag0 >= M) ag0 = M - 1;
  int ag1 = m0 + r1; if (ag1 >= M) ag1 = M - 1;
  const bf16_t* asrc0 = A + (size_t)ag0 * Kp + (sl ^ swz(r0)) * 8;
  const bf16_t* asrc1 = A + (size_t)ag1 * Kp + (sl ^ swz(r1)) * 8;
  const bf16_t* bsrc0 = Bt + (size_t)(n0 + r0) * Kp + (sl ^ swz(r0)) * 8;
  const bf16_t* bsrc1 = Bt + (size_t)(n0 + r1) * Kp + (sl ^ swz(r1)) * 8;

  bf16_t* adst0 = &As[0][0] + wave * 512;
  bf16_t* adst1 = &As[0][0] + 2048 + wave * 512;
  bf16_t* bdst0 = &Bs[0][0] + wave * 512;
  bf16_t* bdst1 = &Bs[0][0] + 2048 + wave * 512;

  int aoff[4], boff[4];
#pragma unroll
  for (int i = 0; i < 4; ++i) {
    int ra = wr + i * 16 + fm;
    aoff[i] = ra * 32 + (fs ^ swz(ra)) * 8;
    int rb = wc + i * 16 + fm;
    boff[i] = rb * 32 + (fs ^ swz(rb)) * 8;
  }

  f32x4 acc[4][4];
#pragma unroll
  for (int i = 0; i < 4; ++i)
#pragma unroll
    for (int j = 0; j < 4; ++j) acc[i][j] = {0.f, 0.f, 0.f, 0.f};

#define STAGES(buf, kof) do { \
    gload_lds16(asrc0 + (kof), adst0 + (buf) * (128 * 32)); \
    gload_lds16(asrc1 + (kof), adst1 + (buf) * (128 * 32)); \
    gload_lds16(bsrc0 + (kof), bdst0 + (buf) * (128 * 32)); \
    gload_lds16(bsrc1 + (kof), bdst1 + (buf) * (128 * 32)); \
  } while (0)

  const int NT = Kp / 32;
  STAGES(0, 0);
  __syncthreads();
  int buf = 0;
  for (int t = 0; t < NT - 1; ++t) {
    STAGES(buf ^ 1, (t + 1) * 32);
    bf16x8 af[4], bfv[4];
#pragma unroll
    for (int i = 0; i < 4; ++i) af[i] = *(const bf16x8*)&As[buf][aoff[i]];
#pragma unroll
    for (int j = 0; j < 4; ++j) bfv[j] = *(const bf16x8*)&Bs[buf][boff[j]];
#pragma unroll
    for (int i = 0; i < 4; ++i)
#pragma unroll
      for (int j = 0; j < 4; ++j)
        acc[i][j] = __builtin_amdgcn_mfma_f32_16x16x32_bf16(af[i], bfv[j], acc[i][j], 0, 0, 0);
    __syncthreads();
    buf ^= 1;
  }
  {
    bf16x8 af[4], bfv[4];
#pragma unroll
    for (int i = 0; i < 4; ++i) af[i] = *(const bf16x8*)&As[buf][aoff[i]];
#pragma unroll
    for (int j = 0; j < 4; ++j) bfv[j] = *(const bf16x8*)&Bs[buf][boff[j]];
#pragma unroll
    for (int i = 0; i < 4; ++i)
#pragma unroll
      for (int j = 0; j < 4; ++j)
        acc[i][j] = __builtin_amdgcn_mfma_f32_16x16x32_bf16(af[i], bfv[j], acc[i][j], 0, 0, 0);
  }

  const int ccol = n0 + wc + fm;
#pragma unroll
  for (int i = 0; i < 4; ++i) {
    const int rb2 = m0 + wr + i * 16 + (lane >> 4) * 4;
#pragma unroll
    for (int r = 0; r < 4; ++r) {
      const int row = rb2 + r;
      if (row < M) {
        bf16_t* cp = C + (size_t)row * N + ccol;
#pragma unroll
        for (int j = 0; j < 4; ++j) {
          float v = acc[i][j][r];
          if (bias) v += bias[ccol + j * 16];
          if (relu) v = fmaxf(v, 0.f);
          cp[j * 16] = (bf16_t)v;
        }
      }
    }
  }
}

// ---------------------------------------------------------------------------
// Weight transpose+convert: src = G stacked [K][256] fp32 -> dst[G*256][Kp] bf16
// ---------------------------------------------------------------------------
__global__ void k_transw(const float* __restrict__ src, bf16_t* __restrict__ dst,
                         int K, int Kp)
{
  __shared__ float tile[32][33];
  const int g = blockIdx.z;
  const int k0 = blockIdx.x * 32, j0 = blockIdx.y * 32;
  const int tx = threadIdx.x, ty = threadIdx.y;  // 32 x 8
  const float* sp = src + (size_t)g * K * 256;
#pragma unroll
  for (int i = 0; i < 4; ++i) {
    int k = k0 + ty + i * 8;
    tile[ty + i * 8][tx] = (k < K) ? sp[(size_t)k * 256 + j0 + tx] : 0.f;
  }
  __syncthreads();
  bf16_t* dp = dst + (size_t)g * 256 * Kp;
#pragma unroll
  for (int i = 0; i < 4; ++i) {
    int n = j0 + ty + i * 8;
    dp[(size_t)n * Kp + k0 + tx] = (bf16_t)tile[tx][ty + i * 8];
  }
}

// ---------------------------------------------------------------------------
// CSR build — merged launches.
// ---------------------------------------------------------------------------
__global__ void k_deg3(const int* __restrict__ e1, const int* __restrict__ e2,
                       const int* __restrict__ e3, int* __restrict__ deg) {
  int i = blockIdx.x * 256 + threadIdx.x;
  if (i >= 3 * NE) return;
  int r = i / NE, e = i - r * NE;
  const int* d = (r == 0 ? e1 : (r == 1 ? e2 : e3)) + NE;
  atomicAdd(&deg[r * NN + d[e]], 1);
}

__global__ void k_degi(const int* __restrict__ i1, const int* __restrict__ i3,
                       int* __restrict__ deg183) {
  int i = blockIdx.x * 256 + threadIdx.x;
  if (i >= 2 * NN) return;
  int r = i / NN, v = i - r * NN;
  int g = (r ? i3 : i1)[v];
  atomicAdd(&deg183[r * NORIG + g], 1);
}

__global__ void k_dinv(const int* __restrict__ deg, float* __restrict__ dinv) {
  int v = blockIdx.x * 256 + threadIdx.x;
  if (v < 3 * NN) dinv[v] = rsqrtf((float)(deg[v] + 1));
}

#define SCAN_T 1024
#define SCAN_CH 20
__global__ __launch_bounds__(SCAN_T) void k_scan(
    const int* __restrict__ deg, int* __restrict__ rp, int* __restrict__ cur)
{
  const int r = blockIdx.x;
  const int* d = deg + r * NN;
  int* rpr = rp + r * (NN + 1);
  int* cr  = cur + r * NN;
  __shared__ int ts[SCAN_T];
  const int t = threadIdx.x;
  const int base = t * SCAN_CH;
  int local[SCAN_CH];
  int sum = 0;
#pragma unroll
  for (int i = 0; i < SCAN_CH; ++i) {
    int v = base + i;
    int x = (v < NN) ? d[v] : 0;
    local[i] = sum; sum += x;
  }
  ts[t] = sum; __syncthreads();
  for (int ofs = 1; ofs < SCAN_T; ofs <<= 1) {
    int v = ts[t];
    int w = (t >= ofs) ? ts[t - ofs] : 0;
    __syncthreads();
    ts[t] = v + w;
    __syncthreads();
  }
  int excl = (t == 0) ? 0 : ts[t - 1];
#pragma unroll
  for (int i = 0; i < SCAN_CH; ++i) {
    int v = base + i;
    if (v < NN) { int val = excl + local[i]; rpr[v] = val; cr[v] = val; }
  }
  if (t == SCAN_T - 1) rpr[NN] = ts[SCAN_T - 1];
}

__global__ void k_scan183(const int* __restrict__ deg183, int* __restrict__ rpg,
                          int* __restrict__ cur183) {
  const int r = blockIdx.x;
  const int* d = deg183 + r * NORIG;
  int* rpr = rpg + r * (NORIG + 1);
  int* cr  = cur183 + r * NORIG;
  __shared__ int ts[256];
  const int t = threadIdx.x;
  int x = (t < NORIG) ? d[t] : 0;
  ts[t] = x; __syncthreads();
  for (int o = 1; o < 256; o <<= 1) {
    int v = ts[t];
    int w = (t >= o) ? ts[t - o] : 0;
    __syncthreads();
    ts[t] = v + w;
    __syncthreads();
  }
  if (t < NORIG) {
    int excl = ts[t] - x;
    rpr[t] = excl; cr[t] = excl;
    if (t == NORIG - 1) rpr[NORIG] = ts[t];
  }
}

__global__ void k_bucket3(const int* __restrict__ e1, const int* __restrict__ e2,
                          const int* __restrict__ e3, int* __restrict__ cur,
                          int* __restrict__ col) {
  int i = blockIdx.x * 256 + threadIdx.x;
  if (i >= 3 * NE) return;
  int r = i / NE, e = i - r * NE;
  const int* ei = (r == 0 ? e1 : (r == 1 ? e2 : e3));
  int d = ei[NE + e];
  int pos = atomicAdd(&cur[r * NN + d], 1);
  col[(size_t)r * NE + pos] = ei[e];
}

__global__ void k_bucketi(const int* __restrict__ i1, const int* __restrict__ i3,
                          int* __restrict__ cur183, int* __restrict__ colg) {
  int i = blockIdx.x * 256 + threadIdx.x;
  if (i >= 2 * NN) return;
  int r = i / NN, v = i - r * NN;
  int g = (r ? i3 : i1)[v];
  int pos = atomicAdd(&cur183[r * NORIG + g], 1);
  colg[r * NN + pos] = v;
}

// ---------------------------------------------------------------------------
// Fused GCN aggregation over PRE-SCALED P (P = H*dinv from GEMM epilogue):
// Out[v] = relu(dv * (P[v] + sum_{s in N(v)} P[s]) + bias), bf16 in/out.
// One wave per (vertex, relation); 16-deep load pipeline.
// ---------------------------------------------------------------------------
__global__ __launch_bounds__(256) void k_gatherb(
    const bf16_t* __restrict__ P, bf16_t* __restrict__ Out,
    const int* __restrict__ rp, const int* __restrict__ col,
    const float* __restrict__ dinv, const float* __restrict__ bias)
{
  const int wv = threadIdx.x >> 6, lane = threadIdx.x & 63;
  const int v = blockIdx.x * 4 + wv;
  const int r = blockIdx.y;
  const int roff = r << 8;
  const int* rpr = rp + r * (NN + 1);
  const int* cr  = col + (size_t)r * NE;
  const float dv = dinv[r * NN + v];
  const int c0 = roff + lane * 4;

  bf16x4 hs = *(const bf16x4*)&P[(size_t)v * 768 + c0];
  float a0 = (float)hs[0], a1 = (float)hs[1], a2 = (float)hs[2], a3 = (float)hs[3];

  int i = rpr[v];
  const int e = rpr[v + 1];
  for (; i + 16 <= e; i += 16) {
    bf16x4 h[16];
#pragma unroll
    for (int u = 0; u < 16; ++u) {
      int s = cr[i + u];
      h[u] = *(const bf16x4*)&P[(size_t)s * 768 + c0];
    }
#pragma unroll
    for (int u = 0; u < 16; ++u) {
      a0 += (float)h[u][0]; a1 += (float)h[u][1];
      a2 += (float)h[u][2]; a3 += (float)h[u][3];
    }
  }
  for (; i + 4 <= e; i += 4) {
    bf16x4 h[4];
#pragma unroll
    for (int u = 0; u < 4; ++u) {
      int s = cr[i + u];
      h[u] = *(const bf16x4*)&P[(size_t)s * 768 + c0];
    }
#pragma unroll
    for (int u = 0; u < 4; ++u) {
      a0 += (float)h[u][0]; a1 += (float)h[u][1];
      a2 += (float)h[u][2]; a3 += (float)h[u][3];
    }
  }
  for (; i < e; ++i) {
    int s = cr[i];
    bf16x4 h = *(const bf16x4*)&P[(size_t)s * 768 + c0];
    a0 += (float)h[0]; a1 += (float)h[1];
    a2 += (float)h[2]; a3 += (float)h[3];
  }
  f32x4 bb = ld4u(bias + c0);
  bf16x4 o;
  o[0] = (bf16_t)fmaxf(dv * a0 + bb[0], 0.f);
  o[1] = (bf16_t)fmaxf(dv * a1 + bb[1], 0.f);
  o[2] = (bf16_t)fmaxf(dv * a2 + bb[2], 0.f);
  o[3] = (bf16_t)fmaxf(dv * a3 + bb[3], 0.f);
  *(bf16x4*)&Out[(size_t)v * 768 + c0] = o;
}

// ---------------------------------------------------------------------------
// Readout: group means via index-CSR (no atomics) + MLP + log_softmax.
// ---------------------------------------------------------------------------
__global__ __launch_bounds__(256) void k_final2(
    const bf16_t* __restrict__ h2,
    const int* __restrict__ rpg, const int* __restrict__ colg,
    const float* __restrict__ mw1, const float* __restrict__ mb1,
    const float* __restrict__ mw2, const float* __restrict__ mb2,
    float* __restrict__ out)
{
  __shared__ float xc[768];
  __shared__ float tt[256];
  __shared__ float lg[8];
  const int g = blockIdx.x, tid = threadIdx.x;
  const int* rp1 = rpg;
  const int* rp3 = rpg + (NORIG + 1);
  const int* c1v = colg;
  const int* c3v = colg + NN;

  float a1 = 0.f;
  int b1 = rp1[g], e1 = rp1[g + 1];
  for (int i = b1; i < e1; ++i) a1 += (float)h2[(size_t)c1v[i] * 256 + tid];
  float a3 = 0.f;
  int b3 = rp3[g], e3 = rp3[g + 1];
  for (int i = b3; i < e3; ++i) a3 += (float)h2[(size_t)c3v[i] * 256 + tid];
  a1 *= 1.f / fmaxf((float)(e1 - b1), 1.f);
  a3 *= 1.f / fmaxf((float)(e3 - b3), 1.f);
  xc[tid] = a1;
  xc[256 + tid] = a3;
  xc[512 + tid] = a3;
  __syncthreads();
  float acc = mb1[tid];
  for (int k = 0; k < 768; ++k) acc += xc[k] * mw1[k * 256 + tid];
  tt[tid] = fmaxf(acc, 0.f);
  __syncthreads();
  if (tid < 7) {
    float a = mb2[tid];
    for (int k = 0; k < 256; ++k) a += tt[k] * mw2[k * 7 + tid];
    lg[tid] = a;
  }
  __syncthreads();
  if (tid == 0) {
    float mx = lg[0];
    for (int c2 = 1; c2 < 7; ++c2) mx = fmaxf(mx, lg[c2]);
    float sum = 0.f;
    for (int c2 = 0; c2 < 7; ++c2) sum += expf(lg[c2] - mx);
    float lse = logf(sum) + mx;
    for (int c2 = 0; c2 < 7; ++c2) out[g * 7 + c2] = lg[c2] - lse;
  }
}

// ---------------------------------------------------------------------------
extern "C" void kernel_launch(void* const* d_in, const int* in_sizes, int n_in,
                              void* d_out, int out_size, void* d_ws, size_t ws_size,
                              hipStream_t stream) {
  const float* x    = (const float*)d_in[0];
  const float* w1   = (const float*)d_in[1];
  const float* b1   = (const float*)d_in[2];
  const float* w2   = (const float*)d_in[3];
  const float* b2   = (const float*)d_in[4];
  const float* m1w1 = (const float*)d_in[5];
  const float* m1b1 = (const float*)d_in[6];
  const float* m1w2 = (const float*)d_in[7];
  const float* m1b2 = (const float*)d_in[8];
  const float* m2w1 = (const float*)d_in[9];
  const float* m2b1 = (const float*)d_in[10];
  const float* m2w2 = (const float*)d_in[11];
  const float* m2b2 = (const float*)d_in[12];
  const float* mw1  = (const float*)d_in[13];
  const float* mb1  = (const float*)d_in[14];
  const float* mw2  = (const float*)d_in[15];
  const float* mb2  = (const float*)d_in[16];
  const int* e1 = (const int*)d_in[17];
  const int* e2 = (const int*)d_in[18];
  const int* e3 = (const int*)d_in[19];
  const int* i1 = (const int*)d_in[20];
  const int* i3 = (const int*)d_in[22];  // index_2 dead in reference (source bug)
  float* out = (float*)d_out;

  char* ws = (char*)d_ws;
  size_t off = 0;
  auto alloc = [&](size_t bytes) {
    char* p = ws + off;
    off += (bytes + 255) & ~(size_t)255;
    return (void*)p;
  };
  bf16_t* xb   = (bf16_t*)alloc((size_t)NN * KP1 * 2);  // 208.6 MB
  bf16_t* wt   = (bf16_t*)alloc((size_t)768 * KP1 * 2); // 8 MB
  bf16_t* a1   = (bf16_t*)alloc((size_t)NN * 768 * 2);
  bf16_t* g1   = (bf16_t*)alloc((size_t)NN * 768 * 2);
  bf16_t* t1   = (bf16_t*)alloc((size_t)NN * 256 * 2);
  bf16_t* h1   = (bf16_t*)alloc((size_t)NN * 256 * 2);
  int*    deg  = (int*)alloc(((size_t)3 * NN + 2 * NORIG) * 4);
  float*  dinv = (float*)alloc((size_t)3 * NN * 4);
  int*    rp   = (int*)alloc((size_t)3 * (NN + 1) * 4);
  int*    cur  = (int*)alloc((size_t)3 * NN * 4);
  int*    col  = (int*)alloc((size_t)3 * NE * 4);
  int*    rpg  = (int*)alloc((size_t)2 * (NORIG + 1) * 4);
  int*    cur183 = (int*)alloc((size_t)2 * NORIG * 4);
  int*    colg = (int*)alloc((size_t)2 * NN * 4);
  int*    deg183 = deg + 3 * NN;

  // ---- CSR build (edges + readout indices) + dinv
  hipMemsetAsync(deg, 0, ((size_t)3 * NN + 2 * NORIG) * 4, stream);
  k_deg3<<<(3 * NE + 255) / 256, 256, 0, stream>>>(e1, e2, e3, deg);
  k_degi<<<(2 * NN + 255) / 256, 256, 0, stream>>>(i1, i3, deg183);
  k_dinv<<<(3 * NN + 255) / 256, 256, 0, stream>>>(deg, dinv);
  k_scan<<<3, SCAN_T, 0, stream>>>(deg, rp, cur);
  k_scan183<<<2, 256, 0, stream>>>(deg183, rpg, cur183);
  k_bucket3<<<(3 * NE + 255) / 256, 256, 0, stream>>>(e1, e2, e3, cur, col);
  k_bucketi<<<(2 * NN + 255) / 256, 256, 0, stream>>>(i1, i3, cur183, colg);

  auto transw = [&](const float* Wsrc, int G, int K, int Kp) {
    k_transw<<<dim3(Kp / 32, 8, G), dim3(32, 8), 0, stream>>>(Wsrc, wt, K, Kp);
  };

  dim3 ggat(NN / 4, 3);
  const int NWGW = 3 * 157;  // flat grid for k_gemm_w (NBX=3, NBY=157)

  // ---- layer 1 (GEMM writes pre-scaled P = H*dinv for the gather)
  transw(w1, 3, FIN, KP1);
  k_cvtpad<<<2048, 256, 0, stream>>>(x, xb);
  k_gemm_w<<<NWGW, 512, 0, stream>>>(xb, wt, a1, nullptr, dinv, NN, 768, KP1, 0, 3);
  k_gatherb<<<ggat, 256, 0, stream>>>(a1, g1, rp, col, dinv, b1);
  transw(m1w1, 1, 768, 768);
  k_gemm_s<<<dim3(2, 157), 256, 0, stream>>>(g1, wt, t1, m1b1, NN, 256, 768, 1);
  transw(m1w2, 1, 256, 256);
  k_gemm_s<<<dim3(2, 157), 256, 0, stream>>>(t1, wt, h1, m1b2, NN, 256, 256, 0);

  // ---- layer 2
  transw(w2, 3, 256, 256);
  k_gemm_w<<<NWGW, 512, 0, stream>>>(h1, wt, a1, nullptr, dinv, NN, 768, 256, 0, 3);
  k_gatherb<<<ggat, 256, 0, stream>>>(a1, g1, rp, col, dinv, b2);
  transw(m2w1, 1, 768, 768);
  k_gemm_s<<<dim3(2, 157), 256, 0, stream>>>(g1, wt, t1, m2b1, NN, 256, 768, 1);
  transw(m2w2, 1, 256, 256);
  k_gemm_s<<<dim3(2, 157), 256, 0, stream>>>(t1, wt, h1, m2b2, NN, 256, 256, 0);

  // ---- readout (atomic-free)
  k_final2<<<NORIG, 256, 0, stream>>>(h1, rpg, colg, mw1, mb1, mw2, mb2, out);
}

// Round 14
// 881.632 us; speedup vs baseline: 1.1564x; 1.0042x over previous
//
#include <hip/hip_runtime.h>
#include <hip/hip_bf16.h>
#include <cstdint>
#include <cstddef>

typedef __bf16 bf16_t;
typedef __bf16 bf16x8 __attribute__((ext_vector_type(8)));
typedef __bf16 bf16x4 __attribute__((ext_vector_type(4)));
typedef float f32x4 __attribute__((ext_vector_type(4)));

#define NN 20000
#define NE 320000
#define FIN 5189
#define KP1 5216   // FIN padded to mult of 32
#define NORIG 183

__device__ inline f32x4 ld4u(const float* p) {
  f32x4 v; __builtin_memcpy(&v, p, 16); return v;
}

__device__ inline void gload_lds16(const bf16_t* g, bf16_t* l) {
  __builtin_amdgcn_global_load_lds(
      (const __attribute__((address_space(1))) uint32_t*)g,
      (__attribute__((address_space(3))) uint32_t*)l, 16, 0, 0);
}

// k-slot swizzle (proven r3-r13): spreads row-starts across banks, 2-way max
__device__ inline int swz(int r) { return (r ^ (r >> 2)) & 3; }

// ---------------------------------------------------------------------------
// x (fp32 [NN][FIN]) -> xb (bf16 [NN][KP1], zero-padded cols)
// ---------------------------------------------------------------------------
__global__ void k_cvtpad(const float* __restrict__ x, bf16_t* __restrict__ xb) {
  const int total = NN * (KP1 / 8);
  for (int idx = blockIdx.x * 256 + threadIdx.x; idx < total; idx += gridDim.x * 256) {
    int row = idx / (KP1 / 8);
    int c8  = idx - row * (KP1 / 8);
    int col = c8 * 8;
    bf16x8 v{};
    const float* xp = x + (size_t)row * FIN + col;
    if (col + 8 <= FIN) {
      f32x4 a = ld4u(xp), b = ld4u(xp + 4);
#pragma unroll
      for (int j = 0; j < 4; ++j) { v[j] = (bf16_t)a[j]; v[4 + j] = (bf16_t)b[j]; }
    } else {
#pragma unroll
      for (int j = 0; j < 8; ++j) v[j] = (col + j < FIN) ? (bf16_t)xp[j] : (bf16_t)0.f;
    }
    *(bf16x8*)&xb[(size_t)row * KP1 + col] = v;
  }
}

// ---------------------------------------------------------------------------
// Wide GEMM: r8 structure (BM=128 BN=256 BK=32, 512 threads) upgraded from
// 2-buffer/syncthreads to 3-buffer counted-vmcnt pipeline (depth-2 prefetch):
// iter u issues STAGE(u+2); end-of-iter waits vmcnt(3) = tile u+1 landed,
// tile u+2's loads stay in flight across the barrier. 72 KB LDS -> 2 blk/CU.
// + T1 XCD swizzle + optional dinv epilogue.
// ---------------------------------------------------------------------------
__global__ __launch_bounds__(512) void k_gemm_w(
    const bf16_t* __restrict__ A, const bf16_t* __restrict__ Bt,
    bf16_t* __restrict__ C, const float* __restrict__ bias,
    const float* __restrict__ dscale,
    int M, int N, int Kp, int relu, int NBX)
{
  __shared__ __align__(16) bf16_t As[3][128 * 32];   // 24 KB
  __shared__ __align__(16) bf16_t Bs[3][256 * 32];   // 48 KB
  // bijective XCD-chunk decode
  const int nwg = gridDim.x;
  const int q = nwg >> 3, rr = nwg & 7;
  const int xcd = blockIdx.x & 7, jj = blockIdx.x >> 3;
  const int L = (xcd < rr ? xcd * (q + 1) : rr * (q + 1) + (xcd - rr) * q) + jj;
  const int bx = L % NBX, by = L / NBX;

  const int tid = threadIdx.x, lane = tid & 63, wave = tid >> 6;
  const int m0 = by * 128, n0 = bx * 256;
  const int wr = (wave >> 2) * 64, wc = (wave & 3) * 64;
  const int fm = lane & 15, fs = lane >> 4;

  const int arow = tid >> 2, asl = tid & 3;
  const int aks = asl ^ swz(arow);
  int agrow = m0 + arow; if (agrow >= M) agrow = M - 1;
  const bf16_t* asrc = A + (size_t)agrow * Kp + aks * 8;

  const int br0 = tid >> 2, br1 = 128 + br0;
  const bf16_t* bsrc0 = Bt + (size_t)(n0 + br0) * Kp + (asl ^ swz(br0)) * 8;
  const bf16_t* bsrc1 = Bt + (size_t)(n0 + br1) * Kp + (asl ^ swz(br1)) * 8;

  bf16_t* adst  = &As[0][0] + wave * 512;
  bf16_t* bdst0 = &Bs[0][0] + wave * 512;
  bf16_t* bdst1 = &Bs[0][0] + 4096 + wave * 512;

  int aoff[4], boff[4];
#pragma unroll
  for (int i = 0; i < 4; ++i) {
    int ra = wr + i * 16 + fm;
    aoff[i] = ra * 32 + (fs ^ swz(ra)) * 8;
    int rb = wc + i * 16 + fm;
    boff[i] = rb * 32 + (fs ^ swz(rb)) * 8;
  }

  f32x4 acc[4][4];
#pragma unroll
  for (int i = 0; i < 4; ++i)
#pragma unroll
    for (int j = 0; j < 4; ++j) acc[i][j] = {0.f, 0.f, 0.f, 0.f};

#define STAGEW(buf, kof) do { \
    gload_lds16(asrc + (kof),  adst  + (buf) * (128 * 32)); \
    gload_lds16(bsrc0 + (kof), bdst0 + (buf) * (256 * 32)); \
    gload_lds16(bsrc1 + (kof), bdst1 + (buf) * (256 * 32)); \
  } while (0)

  const int NT = Kp / 32;   // >= 8 for all call sites
  // prologue: tiles 0 and 1 in flight; wait tile 0 only (3 loads stay out)
  STAGEW(0, 0);
  STAGEW(1, 32);
  __builtin_amdgcn_sched_barrier(0);
  asm volatile("s_waitcnt vmcnt(3)" ::: "memory");
  __builtin_amdgcn_s_barrier();
  __builtin_amdgcn_sched_barrier(0);

  int cb = 0, sb = 2;   // compute buffer (u%3), stage buffer ((u+2)%3)
  for (int u = 0; u < NT; ++u) {
    if (u + 2 < NT) STAGEW(sb, (u + 2) * 32);   // depth-2 prefetch
    bf16x8 af[4], bfv[4];
#pragma unroll
    for (int i = 0; i < 4; ++i) af[i] = *(const bf16x8*)&As[cb][aoff[i]];
#pragma unroll
    for (int j = 0; j < 4; ++j) bfv[j] = *(const bf16x8*)&Bs[cb][boff[j]];
#pragma unroll
    for (int i = 0; i < 4; ++i)
#pragma unroll
      for (int j = 0; j < 4; ++j)
        acc[i][j] = __builtin_amdgcn_mfma_f32_16x16x32_bf16(af[i], bfv[j], acc[i][j], 0, 0, 0);
    if (u + 1 < NT) {
      __builtin_amdgcn_sched_barrier(0);
      if (u + 2 < NT) asm volatile("s_waitcnt vmcnt(3) lgkmcnt(0)" ::: "memory");
      else            asm volatile("s_waitcnt vmcnt(0) lgkmcnt(0)" ::: "memory");
      __builtin_amdgcn_s_barrier();
      __builtin_amdgcn_sched_barrier(0);
    }
    cb = (cb == 2) ? 0 : cb + 1;
    sb = (sb == 2) ? 0 : sb + 1;
  }
#undef STAGEW

  const int ccol = n0 + wc + fm;
  const int rrel = (n0 + wc) >> 8;   // relation block (uniform per wave)
  const float* dsp = dscale ? dscale + (size_t)rrel * NN : nullptr;
#pragma unroll
  for (int i = 0; i < 4; ++i) {
    const int rb2 = m0 + wr + i * 16 + (lane >> 4) * 4;
#pragma unroll
    for (int r = 0; r < 4; ++r) {
      const int row = rb2 + r;
      if (row < M) {
        bf16_t* cp = C + (size_t)row * N + ccol;
        const float sc = dsp ? dsp[row] : 1.f;
#pragma unroll
        for (int j = 0; j < 4; ++j) {
          float v = acc[i][j][r];
          if (bias) v += bias[ccol + j * 16];
          if (relu) v = fmaxf(v, 0.f);
          cp[j * 16] = (bf16_t)(v * sc);
        }
      }
    }
  }
}

// ---------------------------------------------------------------------------
// Small GEMM (proven r4): BM=128 BN=128 BK=32, 256 threads, 2-phase dbuf.
// ---------------------------------------------------------------------------
__global__ __launch_bounds__(256) void k_gemm_s(
    const bf16_t* __restrict__ A, const bf16_t* __restrict__ Bt,
    bf16_t* __restrict__ C, const float* __restrict__ bias,
    int M, int N, int Kp, int relu)
{
  __shared__ __align__(16) bf16_t As[2][128 * 32];
  __shared__ __align__(16) bf16_t Bs[2][128 * 32];
  const int tid = threadIdx.x, lane = tid & 63, wave = tid >> 6;
  const int m0 = blockIdx.y * 128, n0 = blockIdx.x * 128;
  const int wr = (wave >> 1) * 64, wc = (wave & 1) * 64;
  const int fm = lane & 15, fs = lane >> 4;

  const int r0 = tid >> 2, r1 = 64 + r0, sl = tid & 3;
  int ag0 = m0 + r0; if (ag0 >= M) ag0 = M - 1;
  int ag1 = m0 + r1; if (ag1 >= M) ag1 = M - 1;
  const bf16_t* asrc0 = A + (size_t)ag0 * Kp + (sl ^ swz(r0)) * 8;
  const bf16_t* asrc1 = A + (size_t)ag1 * Kp + (sl ^ swz(r1)) * 8;
  const bf16_t* bsrc0 = Bt + (size_t)(n0 + r0) * Kp + (sl ^ swz(r0)) * 8;
  const bf16_t* bsrc1 = Bt + (size_t)(n0 + r1) * Kp + (sl ^ swz(r1)) * 8;

  bf16_t* adst0 = &As[0][0] + wave * 512;
  bf16_t* adst1 = &As[0][0] + 2048 + wave * 512;
  bf16_t* bdst0 = &Bs[0][0] + wave * 512;
  bf16_t* bdst1 = &Bs[0][0] + 2048 + wave * 512;

  int aoff[4], boff[4];
#pragma unroll
  for (int i = 0; i < 4; ++i) {
    int ra = wr + i * 16 + fm;
    aoff[i] = ra * 32 + (fs ^ swz(ra)) * 8;
    int rb = wc + i * 16 + fm;
    boff[i] = rb * 32 + (fs ^ swz(rb)) * 8;
  }

  f32x4 acc[4][4];
#pragma unroll
  for (int i = 0; i < 4; ++i)
#pragma unroll
    for (int j = 0; j < 4; ++j) acc[i][j] = {0.f, 0.f, 0.f, 0.f};

#define STAGES(buf, kof) do { \
    gload_lds16(asrc0 + (kof), adst0 + (buf) * (128 * 32)); \
    gload_lds16(asrc1 + (kof), adst1 + (buf) * (128 * 32)); \
    gload_lds16(bsrc0 + (kof), bdst0 + (buf) * (128 * 32)); \
    gload_lds16(bsrc1 + (kof), bdst1 + (buf) * (128 * 32)); \
  } while (0)

  const int NT = Kp / 32;
  STAGES(0, 0);
  __syncthreads();
  int buf = 0;
  for (int t = 0; t < NT - 1; ++t) {
    STAGES(buf ^ 1, (t + 1) * 32);
    bf16x8 af[4], bfv[4];
#pragma unroll
    for (int i = 0; i < 4; ++i) af[i] = *(const bf16x8*)&As[buf][aoff[i]];
#pragma unroll
    for (int j = 0; j < 4; ++j) bfv[j] = *(const bf16x8*)&Bs[buf][boff[j]];
#pragma unroll
    for (int i = 0; i < 4; ++i)
#pragma unroll
      for (int j = 0; j < 4; ++j)
        acc[i][j] = __builtin_amdgcn_mfma_f32_16x16x32_bf16(af[i], bfv[j], acc[i][j], 0, 0, 0);
    __syncthreads();
    buf ^= 1;
  }
  {
    bf16x8 af[4], bfv[4];
#pragma unroll
    for (int i = 0; i < 4; ++i) af[i] = *(const bf16x8*)&As[buf][aoff[i]];
#pragma unroll
    for (int j = 0; j < 4; ++j) bfv[j] = *(const bf16x8*)&Bs[buf][boff[j]];
#pragma unroll
    for (int i = 0; i < 4; ++i)
#pragma unroll
      for (int j = 0; j < 4; ++j)
        acc[i][j] = __builtin_amdgcn_mfma_f32_16x16x32_bf16(af[i], bfv[j], acc[i][j], 0, 0, 0);
  }

  const int ccol = n0 + wc + fm;
#pragma unroll
  for (int i = 0; i < 4; ++i) {
    const int rb2 = m0 + wr + i * 16 + (lane >> 4) * 4;
#pragma unroll
    for (int r = 0; r < 4; ++r) {
      const int row = rb2 + r;
      if (row < M) {
        bf16_t* cp = C + (size_t)row * N + ccol;
#pragma unroll
        for (int j = 0; j < 4; ++j) {
          float v = acc[i][j][r];
          if (bias) v += bias[ccol + j * 16];
          if (relu) v = fmaxf(v, 0.f);
          cp[j * 16] = (bf16_t)v;
        }
      }
    }
  }
}

// ---------------------------------------------------------------------------
// Weight transpose+convert: src = G stacked [K][256] fp32 -> dst[G*256][Kp] bf16
// ---------------------------------------------------------------------------
__global__ void k_transw(const float* __restrict__ src, bf16_t* __restrict__ dst,
                         int K, int Kp)
{
  __shared__ float tile[32][33];
  const int g = blockIdx.z;
  const int k0 = blockIdx.x * 32, j0 = blockIdx.y * 32;
  const int tx = threadIdx.x, ty = threadIdx.y;  // 32 x 8
  const float* sp = src + (size_t)g * K * 256;
#pragma unroll
  for (int i = 0; i < 4; ++i) {
    int k = k0 + ty + i * 8;
    tile[ty + i * 8][tx] = (k < K) ? sp[(size_t)k * 256 + j0 + tx] : 0.f;
  }
  __syncthreads();
  bf16_t* dp = dst + (size_t)g * 256 * Kp;
#pragma unroll
  for (int i = 0; i < 4; ++i) {
    int n = j0 + ty + i * 8;
    dp[(size_t)n * Kp + k0 + tx] = (bf16_t)tile[tx][ty + i * 8];
  }
}

// ---------------------------------------------------------------------------
// CSR build — merged launches.
// ---------------------------------------------------------------------------
__global__ void k_deg3(const int* __restrict__ e1, const int* __restrict__ e2,
                       const int* __restrict__ e3, int* __restrict__ deg) {
  int i = blockIdx.x * 256 + threadIdx.x;
  if (i >= 3 * NE) return;
  int r = i / NE, e = i - r * NE;
  const int* d = (r == 0 ? e1 : (r == 1 ? e2 : e3)) + NE;
  atomicAdd(&deg[r * NN + d[e]], 1);
}

__global__ void k_degi(const int* __restrict__ i1, const int* __restrict__ i3,
                       int* __restrict__ deg183) {
  int i = blockIdx.x * 256 + threadIdx.x;
  if (i >= 2 * NN) return;
  int r = i / NN, v = i - r * NN;
  int g = (r ? i3 : i1)[v];
  atomicAdd(&deg183[r * NORIG + g], 1);
}

__global__ void k_dinv(const int* __restrict__ deg, float* __restrict__ dinv) {
  int v = blockIdx.x * 256 + threadIdx.x;
  if (v < 3 * NN) dinv[v] = rsqrtf((float)(deg[v] + 1));
}

#define SCAN_T 1024
#define SCAN_CH 20
__global__ __launch_bounds__(SCAN_T) void k_scan(
    const int* __restrict__ deg, int* __restrict__ rp, int* __restrict__ cur)
{
  const int r = blockIdx.x;
  const int* d = deg + r * NN;
  int* rpr = rp + r * (NN + 1);
  int* cr  = cur + r * NN;
  __shared__ int ts[SCAN_T];
  const int t = threadIdx.x;
  const int base = t * SCAN_CH;
  int local[SCAN_CH];
  int sum = 0;
#pragma unroll
  for (int i = 0; i < SCAN_CH; ++i) {
    int v = base + i;
    int x = (v < NN) ? d[v] : 0;
    local[i] = sum; sum += x;
  }
  ts[t] = sum; __syncthreads();
  for (int ofs = 1; ofs < SCAN_T; ofs <<= 1) {
    int v = ts[t];
    int w = (t >= ofs) ? ts[t - ofs] : 0;
    __syncthreads();
    ts[t] = v + w;
    __syncthreads();
  }
  int excl = (t == 0) ? 0 : ts[t - 1];
#pragma unroll
  for (int i = 0; i < SCAN_CH; ++i) {
    int v = base + i;
    if (v < NN) { int val = excl + local[i]; rpr[v] = val; cr[v] = val; }
  }
  if (t == SCAN_T - 1) rpr[NN] = ts[SCAN_T - 1];
}

__global__ void k_scan183(const int* __restrict__ deg183, int* __restrict__ rpg,
                          int* __restrict__ cur183) {
  const int r = blockIdx.x;
  const int* d = deg183 + r * NORIG;
  int* rpr = rpg + r * (NORIG + 1);
  int* cr  = cur183 + r * NORIG;
  __shared__ int ts[256];
  const int t = threadIdx.x;
  int x = (t < NORIG) ? d[t] : 0;
  ts[t] = x; __syncthreads();
  for (int o = 1; o < 256; o <<= 1) {
    int v = ts[t];
    int w = (t >= o) ? ts[t - o] : 0;
    __syncthreads();
    ts[t] = v + w;
    __syncthreads();
  }
  if (t < NORIG) {
    int excl = ts[t] - x;
    rpr[t] = excl; cr[t] = excl;
    if (t == NORIG - 1) rpr[NORIG] = ts[t];
  }
}

__global__ void k_bucket3(const int* __restrict__ e1, const int* __restrict__ e2,
                          const int* __restrict__ e3, int* __restrict__ cur,
                          int* __restrict__ col) {
  int i = blockIdx.x * 256 + threadIdx.x;
  if (i >= 3 * NE) return;
  int r = i / NE, e = i - r * NE;
  const int* ei = (r == 0 ? e1 : (r == 1 ? e2 : e3));
  int d = ei[NE + e];
  int pos = atomicAdd(&cur[r * NN + d], 1);
  col[(size_t)r * NE + pos] = ei[e];
}

__global__ void k_bucketi(const int* __restrict__ i1, const int* __restrict__ i3,
                          int* __restrict__ cur183, int* __restrict__ colg) {
  int i = blockIdx.x * 256 + threadIdx.x;
  if (i >= 2 * NN) return;
  int r = i / NN, v = i - r * NN;
  int g = (r ? i3 : i1)[v];
  int pos = atomicAdd(&cur183[r * NORIG + g], 1);
  colg[r * NN + pos] = v;
}

// ---------------------------------------------------------------------------
// Fused GCN aggregation over PRE-SCALED P (P = H*dinv from GEMM epilogue):
// Out[v] = relu(dv * (P[v] + sum_{s in N(v)} P[s]) + bias), bf16 in/out.
// ---------------------------------------------------------------------------
__global__ __launch_bounds__(256) void k_gatherb(
    const bf16_t* __restrict__ P, bf16_t* __restrict__ Out,
    const int* __restrict__ rp, const int* __restrict__ col,
    const float* __restrict__ dinv, const float* __restrict__ bias)
{
  const int wv = threadIdx.x >> 6, lane = threadIdx.x & 63;
  const int v = blockIdx.x * 4 + wv;
  const int r = blockIdx.y;
  const int roff = r << 8;
  const int* rpr = rp + r * (NN + 1);
  const int* cr  = col + (size_t)r * NE;
  const float dv = dinv[r * NN + v];
  const int c0 = roff + lane * 4;

  bf16x4 hs = *(const bf16x4*)&P[(size_t)v * 768 + c0];
  float a0 = (float)hs[0], a1 = (float)hs[1], a2 = (float)hs[2], a3 = (float)hs[3];

  int i = rpr[v];
  const int e = rpr[v + 1];
  for (; i + 16 <= e; i += 16) {
    bf16x4 h[16];
#pragma unroll
    for (int u = 0; u < 16; ++u) {
      int s = cr[i + u];
      h[u] = *(const bf16x4*)&P[(size_t)s * 768 + c0];
    }
#pragma unroll
    for (int u = 0; u < 16; ++u) {
      a0 += (float)h[u][0]; a1 += (float)h[u][1];
      a2 += (float)h[u][2]; a3 += (float)h[u][3];
    }
  }
  for (; i + 4 <= e; i += 4) {
    bf16x4 h[4];
#pragma unroll
    for (int u = 0; u < 4; ++u) {
      int s = cr[i + u];
      h[u] = *(const bf16x4*)&P[(size_t)s * 768 + c0];
    }
#pragma unroll
    for (int u = 0; u < 4; ++u) {
      a0 += (float)h[u][0]; a1 += (float)h[u][1];
      a2 += (float)h[u][2]; a3 += (float)h[u][3];
    }
  }
  for (; i < e; ++i) {
    int s = cr[i];
    bf16x4 h = *(const bf16x4*)&P[(size_t)s * 768 + c0];
    a0 += (float)h[0]; a1 += (float)h[1];
    a2 += (float)h[2]; a3 += (float)h[3];
  }
  f32x4 bb = ld4u(bias + c0);
  bf16x4 o;
  o[0] = (bf16_t)fmaxf(dv * a0 + bb[0], 0.f);
  o[1] = (bf16_t)fmaxf(dv * a1 + bb[1], 0.f);
  o[2] = (bf16_t)fmaxf(dv * a2 + bb[2], 0.f);
  o[3] = (bf16_t)fmaxf(dv * a3 + bb[3], 0.f);
  *(bf16x4*)&Out[(size_t)v * 768 + c0] = o;
}

// ---------------------------------------------------------------------------
// Readout: group means via index-CSR (no atomics) + MLP + log_softmax.
// ---------------------------------------------------------------------------
__global__ __launch_bounds__(256) void k_final2(
    const bf16_t* __restrict__ h2,
    const int* __restrict__ rpg, const int* __restrict__ colg,
    const float* __restrict__ mw1, const float* __restrict__ mb1,
    const float* __restrict__ mw2, const float* __restrict__ mb2,
    float* __restrict__ out)
{
  __shared__ float xc[768];
  __shared__ float tt[256];
  __shared__ float lg[8];
  const int g = blockIdx.x, tid = threadIdx.x;
  const int* rp1 = rpg;
  const int* rp3 = rpg + (NORIG + 1);
  const int* c1v = colg;
  const int* c3v = colg + NN;

  float a1 = 0.f;
  int b1 = rp1[g], e1 = rp1[g + 1];
  for (int i = b1; i < e1; ++i) a1 += (float)h2[(size_t)c1v[i] * 256 + tid];
  float a3 = 0.f;
  int b3 = rp3[g], e3 = rp3[g + 1];
  for (int i = b3; i < e3; ++i) a3 += (float)h2[(size_t)c3v[i] * 256 + tid];
  a1 *= 1.f / fmaxf((float)(e1 - b1), 1.f);
  a3 *= 1.f / fmaxf((float)(e3 - b3), 1.f);
  xc[tid] = a1;
  xc[256 + tid] = a3;
  xc[512 + tid] = a3;
  __syncthreads();
  float acc = mb1[tid];
  for (int k = 0; k < 768; ++k) acc += xc[k] * mw1[k * 256 + tid];
  tt[tid] = fmaxf(acc, 0.f);
  __syncthreads();
  if (tid < 7) {
    float a = mb2[tid];
    for (int k = 0; k < 256; ++k) a += tt[k] * mw2[k * 7 + tid];
    lg[tid] = a;
  }
  __syncthreads();
  if (tid == 0) {
    float mx = lg[0];
    for (int c2 = 1; c2 < 7; ++c2) mx = fmaxf(mx, lg[c2]);
    float sum = 0.f;
    for (int c2 = 0; c2 < 7; ++c2) sum += expf(lg[c2] - mx);
    float lse = logf(sum) + mx;
    for (int c2 = 0; c2 < 7; ++c2) out[g * 7 + c2] = lg[c2] - lse;
  }
}

// ---------------------------------------------------------------------------
extern "C" void kernel_launch(void* const* d_in, const int* in_sizes, int n_in,
                              void* d_out, int out_size, void* d_ws, size_t ws_size,
                              hipStream_t stream) {
  const float* x    = (const float*)d_in[0];
  const float* w1   = (const float*)d_in[1];
  const float* b1   = (const float*)d_in[2];
  const float* w2   = (const float*)d_in[3];
  const float* b2   = (const float*)d_in[4];
  const float* m1w1 = (const float*)d_in[5];
  const float* m1b1 = (const float*)d_in[6];
  const float* m1w2 = (const float*)d_in[7];
  const float* m1b2 = (const float*)d_in[8];
  const float* m2w1 = (const float*)d_in[9];
  const float* m2b1 = (const float*)d_in[10];
  const float* m2w2 = (const float*)d_in[11];
  const float* m2b2 = (const float*)d_in[12];
  const float* mw1  = (const float*)d_in[13];
  const float* mb1  = (const float*)d_in[14];
  const float* mw2  = (const float*)d_in[15];
  const float* mb2  = (const float*)d_in[16];
  const int* e1 = (const int*)d_in[17];
  const int* e2 = (const int*)d_in[18];
  const int* e3 = (const int*)d_in[19];
  const int* i1 = (const int*)d_in[20];
  const int* i3 = (const int*)d_in[22];  // index_2 dead in reference (source bug)
  float* out = (float*)d_out;

  char* ws = (char*)d_ws;
  size_t off = 0;
  auto alloc = [&](size_t bytes) {
    char* p = ws + off;
    off += (bytes + 255) & ~(size_t)255;
    return (void*)p;
  };
  bf16_t* xb   = (bf16_t*)alloc((size_t)NN * KP1 * 2);  // 208.6 MB
  bf16_t* wt   = (bf16_t*)alloc((size_t)768 * KP1 * 2); // 8 MB
  bf16_t* a1   = (bf16_t*)alloc((size_t)NN * 768 * 2);
  bf16_t* g1   = (bf16_t*)alloc((size_t)NN * 768 * 2);
  bf16_t* t1   = (bf16_t*)alloc((size_t)NN * 256 * 2);
  bf16_t* h1   = (bf16_t*)alloc((size_t)NN * 256 * 2);
  int*    deg  = (int*)alloc(((size_t)3 * NN + 2 * NORIG) * 4);
  float*  dinv = (float*)alloc((size_t)3 * NN * 4);
  int*    rp   = (int*)alloc((size_t)3 * (NN + 1) * 4);
  int*    cur  = (int*)alloc((size_t)3 * NN * 4);
  int*    col  = (int*)alloc((size_t)3 * NE * 4);
  int*    rpg  = (int*)alloc((size_t)2 * (NORIG + 1) * 4);
  int*    cur183 = (int*)alloc((size_t)2 * NORIG * 4);
  int*    colg = (int*)alloc((size_t)2 * NN * 4);
  int*    deg183 = deg + 3 * NN;

  // ---- CSR build (edges + readout indices) + dinv
  hipMemsetAsync(deg, 0, ((size_t)3 * NN + 2 * NORIG) * 4, stream);
  k_deg3<<<(3 * NE + 255) / 256, 256, 0, stream>>>(e1, e2, e3, deg);
  k_degi<<<(2 * NN + 255) / 256, 256, 0, stream>>>(i1, i3, deg183);
  k_dinv<<<(3 * NN + 255) / 256, 256, 0, stream>>>(deg, dinv);
  k_scan<<<3, SCAN_T, 0, stream>>>(deg, rp, cur);
  k_scan183<<<2, 256, 0, stream>>>(deg183, rpg, cur183);
  k_bucket3<<<(3 * NE + 255) / 256, 256, 0, stream>>>(e1, e2, e3, cur, col);
  k_bucketi<<<(2 * NN + 255) / 256, 256, 0, stream>>>(i1, i3, cur183, colg);

  auto transw = [&](const float* Wsrc, int G, int K, int Kp) {
    k_transw<<<dim3(Kp / 32, 8, G), dim3(32, 8), 0, stream>>>(Wsrc, wt, K, Kp);
  };

  dim3 ggat(NN / 4, 3);
  const int NWGW = 3 * 157;  // flat grid for k_gemm_w (NBX=3, NBY=157)

  // ---- layer 1 (GEMM writes pre-scaled P = H*dinv for the gather)
  transw(w1, 3, FIN, KP1);
  k_cvtpad<<<2048, 256, 0, stream>>>(x, xb);
  k_gemm_w<<<NWGW, 512, 0, stream>>>(xb, wt, a1, nullptr, dinv, NN, 768, KP1, 0, 3);
  k_gatherb<<<ggat, 256, 0, stream>>>(a1, g1, rp, col, dinv, b1);
  transw(m1w1, 1, 768, 768);
  k_gemm_s<<<dim3(2, 157), 256, 0, stream>>>(g1, wt, t1, m1b1, NN, 256, 768, 1);
  transw(m1w2, 1, 256, 256);
  k_gemm_s<<<dim3(2, 157), 256, 0, stream>>>(t1, wt, h1, m1b2, NN, 256, 256, 0);

  // ---- layer 2
  transw(w2, 3, 256, 256);
  k_gemm_w<<<NWGW, 512, 0, stream>>>(h1, wt, a1, nullptr, dinv, NN, 768, 256, 0, 3);
  k_gatherb<<<ggat, 256, 0, stream>>>(a1, g1, rp, col, dinv, b2);
  transw(m2w1, 1, 768, 768);
  k_gemm_s<<<dim3(2, 157), 256, 0, stream>>>(g1, wt, t1, m2b1, NN, 256, 768, 1);
  transw(m2w2, 1, 256, 256);
  k_gemm_s<<<dim3(2, 157), 256, 0, stream>>>(t1, wt, h1, m2b2, NN, 256, 256, 0);

  // ---- readout (atomic-free)
  k_final2<<<NORIG, 256, 0, stream>>>(h1, rpg, colg, mw1, mb1, mw2, mb2, out);
}

// Round 16
// 866.806 us; speedup vs baseline: 1.1762x; 1.0171x over previous
//
#include <hip/hip_runtime.h>
#include <hip/hip_bf16.h>
#include <cstdint>
#include <cstddef>

typedef __bf16 bf16_t;
typedef __bf16 bf16x8 __attribute__((ext_vector_type(8)));
typedef __bf16 bf16x4 __attribute__((ext_vector_type(4)));
typedef float f32x4 __attribute__((ext_vector_type(4)));

#define NN 20000
#define NE 320000
#define FIN 5189
#define KP1 5216   // FIN padded to mult of 32
#define NORIG 183

__device__ inline f32x4 ld4u(const float* p) {
  f32x4 v; __builtin_memcpy(&v, p, 16); return v;
}

__device__ inline void gload_lds16(const bf16_t* g, bf16_t* l) {
  __builtin_amdgcn_global_load_lds(
      (const __attribute__((address_space(1))) uint32_t*)g,
      (__attribute__((address_space(3))) uint32_t*)l, 16, 0, 0);
}

// k-slot swizzle (proven r3-r14): spreads row-starts across banks, 2-way max
__device__ inline int swz(int r) { return (r ^ (r >> 2)) & 3; }

// ---------------------------------------------------------------------------
// x (fp32 [NN][FIN]) -> xb (bf16 [NN][KP1], zero-padded cols)
// ---------------------------------------------------------------------------
__global__ void k_cvtpad(const float* __restrict__ x, bf16_t* __restrict__ xb) {
  const int total = NN * (KP1 / 8);
  for (int idx = blockIdx.x * 256 + threadIdx.x; idx < total; idx += gridDim.x * 256) {
    int row = idx / (KP1 / 8);
    int c8  = idx - row * (KP1 / 8);
    int col = c8 * 8;
    bf16x8 v{};
    const float* xp = x + (size_t)row * FIN + col;
    if (col + 8 <= FIN) {
      f32x4 a = ld4u(xp), b = ld4u(xp + 4);
#pragma unroll
      for (int j = 0; j < 4; ++j) { v[j] = (bf16_t)a[j]; v[4 + j] = (bf16_t)b[j]; }
    } else {
#pragma unroll
      for (int j = 0; j < 8; ++j) v[j] = (col + j < FIN) ? (bf16_t)xp[j] : (bf16_t)0.f;
    }
    *(bf16x8*)&xb[(size_t)row * KP1 + col] = v;
  }
}

// ---------------------------------------------------------------------------
// Wide GEMM: r14 3-buffer counted-vmcnt pipeline (measured == r8 2-phase).
// BM=128 BN=256 BK=32, 512 threads, T1 swizzle, dinv epilogue.
// ---------------------------------------------------------------------------
__global__ __launch_bounds__(512) void k_gemm_w(
    const bf16_t* __restrict__ A, const bf16_t* __restrict__ Bt,
    bf16_t* __restrict__ C, const float* __restrict__ bias,
    const float* __restrict__ dscale,
    int M, int N, int Kp, int relu, int NBX)
{
  __shared__ __align__(16) bf16_t As[3][128 * 32];   // 24 KB
  __shared__ __align__(16) bf16_t Bs[3][256 * 32];   // 48 KB
  const int nwg = gridDim.x;
  const int q = nwg >> 3, rr = nwg & 7;
  const int xcd = blockIdx.x & 7, jj = blockIdx.x >> 3;
  const int L = (xcd < rr ? xcd * (q + 1) : rr * (q + 1) + (xcd - rr) * q) + jj;
  const int bx = L % NBX, by = L / NBX;

  const int tid = threadIdx.x, lane = tid & 63, wave = tid >> 6;
  const int m0 = by * 128, n0 = bx * 256;
  const int wr = (wave >> 2) * 64, wc = (wave & 3) * 64;
  const int fm = lane & 15, fs = lane >> 4;

  const int arow = tid >> 2, asl = tid & 3;
  const int aks = asl ^ swz(arow);
  int agrow = m0 + arow; if (agrow >= M) agrow = M - 1;
  const bf16_t* asrc = A + (size_t)agrow * Kp + aks * 8;

  const int br0 = tid >> 2, br1 = 128 + br0;
  const bf16_t* bsrc0 = Bt + (size_t)(n0 + br0) * Kp + (asl ^ swz(br0)) * 8;
  const bf16_t* bsrc1 = Bt + (size_t)(n0 + br1) * Kp + (asl ^ swz(br1)) * 8;

  bf16_t* adst  = &As[0][0] + wave * 512;
  bf16_t* bdst0 = &Bs[0][0] + wave * 512;
  bf16_t* bdst1 = &Bs[0][0] + 4096 + wave * 512;

  int aoff[4], boff[4];
#pragma unroll
  for (int i = 0; i < 4; ++i) {
    int ra = wr + i * 16 + fm;
    aoff[i] = ra * 32 + (fs ^ swz(ra)) * 8;
    int rb = wc + i * 16 + fm;
    boff[i] = rb * 32 + (fs ^ swz(rb)) * 8;
  }

  f32x4 acc[4][4];
#pragma unroll
  for (int i = 0; i < 4; ++i)
#pragma unroll
    for (int j = 0; j < 4; ++j) acc[i][j] = {0.f, 0.f, 0.f, 0.f};

#define STAGEW(buf, kof) do { \
    gload_lds16(asrc + (kof),  adst  + (buf) * (128 * 32)); \
    gload_lds16(bsrc0 + (kof), bdst0 + (buf) * (256 * 32)); \
    gload_lds16(bsrc1 + (kof), bdst1 + (buf) * (256 * 32)); \
  } while (0)

  const int NT = Kp / 32;
  STAGEW(0, 0);
  STAGEW(1, 32);
  __builtin_amdgcn_sched_barrier(0);
  asm volatile("s_waitcnt vmcnt(3)" ::: "memory");
  __builtin_amdgcn_s_barrier();
  __builtin_amdgcn_sched_barrier(0);

  int cb = 0, sb = 2;
  for (int u = 0; u < NT; ++u) {
    if (u + 2 < NT) STAGEW(sb, (u + 2) * 32);
    bf16x8 af[4], bfv[4];
#pragma unroll
    for (int i = 0; i < 4; ++i) af[i] = *(const bf16x8*)&As[cb][aoff[i]];
#pragma unroll
    for (int j = 0; j < 4; ++j) bfv[j] = *(const bf16x8*)&Bs[cb][boff[j]];
#pragma unroll
    for (int i = 0; i < 4; ++i)
#pragma unroll
      for (int j = 0; j < 4; ++j)
        acc[i][j] = __builtin_amdgcn_mfma_f32_16x16x32_bf16(af[i], bfv[j], acc[i][j], 0, 0, 0);
    if (u + 1 < NT) {
      __builtin_amdgcn_sched_barrier(0);
      if (u + 2 < NT) asm volatile("s_waitcnt vmcnt(3) lgkmcnt(0)" ::: "memory");
      else            asm volatile("s_waitcnt vmcnt(0) lgkmcnt(0)" ::: "memory");
      __builtin_amdgcn_s_barrier();
      __builtin_amdgcn_sched_barrier(0);
    }
    cb = (cb == 2) ? 0 : cb + 1;
    sb = (sb == 2) ? 0 : sb + 1;
  }
#undef STAGEW

  const int ccol = n0 + wc + fm;
  const int rrel = (n0 + wc) >> 8;
  const float* dsp = dscale ? dscale + (size_t)rrel * NN : nullptr;
#pragma unroll
  for (int i = 0; i < 4; ++i) {
    const int rb2 = m0 + wr + i * 16 + (lane >> 4) * 4;
#pragma unroll
    for (int r = 0; r < 4; ++r) {
      const int row = rb2 + r;
      if (row < M) {
        bf16_t* cp = C + (size_t)row * N + ccol;
        const float sc = dsp ? dsp[row] : 1.f;
#pragma unroll
        for (int j = 0; j < 4; ++j) {
          float v = acc[i][j][r];
          if (bias) v += bias[ccol + j * 16];
          if (relu) v = fmaxf(v, 0.f);
          cp[j * 16] = (bf16_t)(v * sc);
        }
      }
    }
  }
}

// ---------------------------------------------------------------------------
// Small GEMM (proven r4): BM=128 BN=128 BK=32, 256 threads, 2-phase dbuf.
// ---------------------------------------------------------------------------
__global__ __launch_bounds__(256) void k_gemm_s(
    const bf16_t* __restrict__ A, const bf16_t* __restrict__ Bt,
    bf16_t* __restrict__ C, const float* __restrict__ bias,
    int M, int N, int Kp, int relu)
{
  __shared__ __align__(16) bf16_t As[2][128 * 32];
  __shared__ __align__(16) bf16_t Bs[2][128 * 32];
  const int tid = threadIdx.x, lane = tid & 63, wave = tid >> 6;
  const int m0 = blockIdx.y * 128, n0 = blockIdx.x * 128;
  const int wr = (wave >> 1) * 64, wc = (wave & 1) * 64;
  const int fm = lane & 15, fs = lane >> 4;

  const int r0 = tid >> 2, r1 = 64 + r0, sl = tid & 3;
  int ag0 = m0 + r0; if (ag0 >= M) ag0 = M - 1;
  int ag1 = m0 + r1; if (ag1 >= M) ag1 = M - 1;
  const bf16_t* asrc0 = A + (size_t)ag0 * Kp + (sl ^ swz(r0)) * 8;
  const bf16_t* asrc1 = A + (size_t)ag1 * Kp + (sl ^ swz(r1)) * 8;
  const bf16_t* bsrc0 = Bt + (size_t)(n0 + r0) * Kp + (sl ^ swz(r0)) * 8;
  const bf16_t* bsrc1 = Bt + (size_t)(n0 + r1) * Kp + (sl ^ swz(r1)) * 8;

  bf16_t* adst0 = &As[0][0] + wave * 512;
  bf16_t* adst1 = &As[0][0] + 2048 + wave * 512;
  bf16_t* bdst0 = &Bs[0][0] + wave * 512;
  bf16_t* bdst1 = &Bs[0][0] + 2048 + wave * 512;

  int aoff[4], boff[4];
#pragma unroll
  for (int i = 0; i < 4; ++i) {
    int ra = wr + i * 16 + fm;
    aoff[i] = ra * 32 + (fs ^ swz(ra)) * 8;
    int rb = wc + i * 16 + fm;
    boff[i] = rb * 32 + (fs ^ swz(rb)) * 8;
  }

  f32x4 acc[4][4];
#pragma unroll
  for (int i = 0; i < 4; ++i)
#pragma unroll
    for (int j = 0; j < 4; ++j) acc[i][j] = {0.f, 0.f, 0.f, 0.f};

#define STAGES(buf, kof) do { \
    gload_lds16(asrc0 + (kof), adst0 + (buf) * (128 * 32)); \
    gload_lds16(asrc1 + (kof), adst1 + (buf) * (128 * 32)); \
    gload_lds16(bsrc0 + (kof), bdst0 + (buf) * (128 * 32)); \
    gload_lds16(bsrc1 + (kof), bdst1 + (buf) * (128 * 32)); \
  } while (0)

  const int NT = Kp / 32;
  STAGES(0, 0);
  __syncthreads();
  int buf = 0;
  for (int t = 0; t < NT - 1; ++t) {
    STAGES(buf ^ 1, (t + 1) * 32);
    bf16x8 af[4], bfv[4];
#pragma unroll
    for (int i = 0; i < 4; ++i) af[i] = *(const bf16x8*)&As[buf][aoff[i]];
#pragma unroll
    for (int j = 0; j < 4; ++j) bfv[j] = *(const bf16x8*)&Bs[buf][boff[j]];
#pragma unroll
    for (int i = 0; i < 4; ++i)
#pragma unroll
      for (int j = 0; j < 4; ++j)
        acc[i][j] = __builtin_amdgcn_mfma_f32_16x16x32_bf16(af[i], bfv[j], acc[i][j], 0, 0, 0);
    __syncthreads();
    buf ^= 1;
  }
  {
    bf16x8 af[4], bfv[4];
#pragma unroll
    for (int i = 0; i < 4; ++i) af[i] = *(const bf16x8*)&As[buf][aoff[i]];
#pragma unroll
    for (int j = 0; j < 4; ++j) bfv[j] = *(const bf16x8*)&Bs[buf][boff[j]];
#pragma unroll
    for (int i = 0; i < 4; ++i)
#pragma unroll
      for (int j = 0; j < 4; ++j)
        acc[i][j] = __builtin_amdgcn_mfma_f32_16x16x32_bf16(af[i], bfv[j], acc[i][j], 0, 0, 0);
  }

  const int ccol = n0 + wc + fm;
#pragma unroll
  for (int i = 0; i < 4; ++i) {
    const int rb2 = m0 + wr + i * 16 + (lane >> 4) * 4;
#pragma unroll
    for (int r = 0; r < 4; ++r) {
      const int row = rb2 + r;
      if (row < M) {
        bf16_t* cp = C + (size_t)row * N + ccol;
#pragma unroll
        for (int j = 0; j < 4; ++j) {
          float v = acc[i][j][r];
          if (bias) v += bias[ccol + j * 16];
          if (relu) v = fmaxf(v, 0.f);
          cp[j * 16] = (bf16_t)v;
        }
      }
    }
  }
}

// ---------------------------------------------------------------------------
// Weight transpose+convert, w1 only: [K][256]x3 fp32 -> [3*256][Kp] bf16
// ---------------------------------------------------------------------------
__global__ void k_transw(const float* __restrict__ src, bf16_t* __restrict__ dst,
                         int K, int Kp)
{
  __shared__ float tile[32][33];
  const int g = blockIdx.z;
  const int k0 = blockIdx.x * 32, j0 = blockIdx.y * 32;
  const int tx = threadIdx.x, ty = threadIdx.y;  // 32 x 8
  const float* sp = src + (size_t)g * K * 256;
#pragma unroll
  for (int i = 0; i < 4; ++i) {
    int k = k0 + ty + i * 8;
    tile[ty + i * 8][tx] = (k < K) ? sp[(size_t)k * 256 + j0 + tx] : 0.f;
  }
  __syncthreads();
  bf16_t* dp = dst + (size_t)g * 256 * Kp;
#pragma unroll
  for (int i = 0; i < 4; ++i) {
    int n = j0 + ty + i * 8;
    dp[(size_t)n * Kp + k0 + tx] = (bf16_t)tile[tx][ty + i * 8];
  }
}

// ---------------------------------------------------------------------------
// Merged transpose of the 5 small weights (one launch, z selects weight):
// z0:m1w1(768) z1:m1w2(256) z2-4:w2 slab(256) z5:m2w1(768) z6:m2w2(256)
// ---------------------------------------------------------------------------
__global__ void k_transw5(
    const float* __restrict__ m1w1, const float* __restrict__ m1w2,
    const float* __restrict__ w2,   const float* __restrict__ m2w1,
    const float* __restrict__ m2w2,
    bf16_t* __restrict__ d_m1w1, bf16_t* __restrict__ d_m1w2,
    bf16_t* __restrict__ d_w2,   bf16_t* __restrict__ d_m2w1,
    bf16_t* __restrict__ d_m2w2)
{
  const int z = blockIdx.z;
  const float* src; bf16_t* dst; int K;
  switch (z) {
    case 0: src = m1w1; dst = d_m1w1; K = 768; break;
    case 1: src = m1w2; dst = d_m1w2; K = 256; break;
    case 2: case 3: case 4:
      src = w2 + (size_t)(z - 2) * 256 * 256;
      dst = d_w2 + (size_t)(z - 2) * 256 * 256; K = 256; break;
    case 5: src = m2w1; dst = d_m2w1; K = 768; break;
    default: src = m2w2; dst = d_m2w2; K = 256; break;
  }
  const int k0 = blockIdx.x * 32, j0 = blockIdx.y * 32;
  if (k0 >= K) return;
  __shared__ float tile[32][33];
  const int tx = threadIdx.x, ty = threadIdx.y;
#pragma unroll
  for (int i = 0; i < 4; ++i) {
    int k = k0 + ty + i * 8;
    tile[ty + i * 8][tx] = (k < K) ? src[(size_t)k * 256 + j0 + tx] : 0.f;
  }
  __syncthreads();
#pragma unroll
  for (int i = 0; i < 4; ++i) {
    int n = j0 + ty + i * 8;
    dst[(size_t)n * K + k0 + tx] = (bf16_t)tile[tx][ty + i * 8];
  }
}

// ---------------------------------------------------------------------------
// Merged degree histogram: edges (3*NE) then readout indices (2*NN)
// ---------------------------------------------------------------------------
__global__ void k_degall(const int* __restrict__ e1, const int* __restrict__ e2,
                         const int* __restrict__ e3, const int* __restrict__ i1,
                         const int* __restrict__ i3, int* __restrict__ deg,
                         int* __restrict__ deg183) {
  int i = blockIdx.x * 256 + threadIdx.x;
  if (i < 3 * NE) {
    int r = i / NE, e = i - r * NE;
    const int* d = (r == 0 ? e1 : (r == 1 ? e2 : e3)) + NE;
    atomicAdd(&deg[r * NN + d[e]], 1);
  } else {
    int j = i - 3 * NE;
    if (j < 2 * NN) {
      int r = j / NN, v = j - r * NN;
      int g = (r ? i3 : i1)[v];
      atomicAdd(&deg183[r * NORIG + g], 1);
    }
  }
}

// ---------------------------------------------------------------------------
// Merged exclusive scans: blocks 0-2 vertex scans (+dinv), blocks 3-4 group.
// ---------------------------------------------------------------------------
#define SCAN_T 1024
#define SCAN_CH 20
__global__ __launch_bounds__(SCAN_T) void k_scanall(
    const int* __restrict__ deg, const int* __restrict__ deg183,
    int* __restrict__ rp, int* __restrict__ cur,
    int* __restrict__ rpg, int* __restrict__ cur183,
    float* __restrict__ dinv)
{
  const int b = blockIdx.x;
  const int* d; int n; int* rpr; int* cr; float* dv = nullptr;
  if (b < 3) { d = deg + b * NN; n = NN; rpr = rp + b * (NN + 1); cr = cur + b * NN; dv = dinv + b * NN; }
  else { int r = b - 3; d = deg183 + r * NORIG; n = NORIG; rpr = rpg + r * (NORIG + 1); cr = cur183 + r * NORIG; }

  __shared__ int ts[SCAN_T];
  const int t = threadIdx.x;
  const int base = t * SCAN_CH;
  int local[SCAN_CH];
  int sum = 0;
#pragma unroll
  for (int i = 0; i < SCAN_CH; ++i) {
    int v = base + i;
    int x = (v < n) ? d[v] : 0;
    if (dv && v < n) dv[v] = rsqrtf((float)(x + 1));
    local[i] = sum; sum += x;
  }
  ts[t] = sum; __syncthreads();
  for (int ofs = 1; ofs < SCAN_T; ofs <<= 1) {
    int v = ts[t];
    int w = (t >= ofs) ? ts[t - ofs] : 0;
    __syncthreads();
    ts[t] = v + w;
    __syncthreads();
  }
  int excl = (t == 0) ? 0 : ts[t - 1];
#pragma unroll
  for (int i = 0; i < SCAN_CH; ++i) {
    int v = base + i;
    if (v < n) { int val = excl + local[i]; rpr[v] = val; cr[v] = val; }
  }
  if (t == SCAN_T - 1) rpr[n] = ts[SCAN_T - 1];
}

// ---------------------------------------------------------------------------
// Merged bucket fill: edges then readout indices.
// ---------------------------------------------------------------------------
__global__ void k_bucketall(const int* __restrict__ e1, const int* __restrict__ e2,
                            const int* __restrict__ e3, const int* __restrict__ i1,
                            const int* __restrict__ i3, int* __restrict__ cur,
                            int* __restrict__ col, int* __restrict__ cur183,
                            int* __restrict__ colg) {
  int i = blockIdx.x * 256 + threadIdx.x;
  if (i < 3 * NE) {
    int r = i / NE, e = i - r * NE;
    const int* ei = (r == 0 ? e1 : (r == 1 ? e2 : e3));
    int d = ei[NE + e];
    int pos = atomicAdd(&cur[r * NN + d], 1);
    col[(size_t)r * NE + pos] = ei[e];
  } else {
    int j = i - 3 * NE;
    if (j < 2 * NN) {
      int r = j / NN, v = j - r * NN;
      int g = (r ? i3 : i1)[v];
      int pos = atomicAdd(&cur183[r * NORIG + g], 1);
      colg[r * NN + pos] = v;
    }
  }
}

// ---------------------------------------------------------------------------
// Fused GCN aggregation over PRE-SCALED P (P = H*dinv from GEMM epilogue):
// Out[v] = relu(dv * (P[v] + sum_{s in N(v)} P[s]) + bias), bf16 in/out.
// ---------------------------------------------------------------------------
__global__ __launch_bounds__(256) void k_gatherb(
    const bf16_t* __restrict__ P, bf16_t* __restrict__ Out,
    const int* __restrict__ rp, const int* __restrict__ col,
    const float* __restrict__ dinv, const float* __restrict__ bias)
{
  const int wv = threadIdx.x >> 6, lane = threadIdx.x & 63;
  const int v = blockIdx.x * 4 + wv;
  const int r = blockIdx.y;
  const int roff = r << 8;
  const int* rpr = rp + r * (NN + 1);
  const int* cr  = col + (size_t)r * NE;
  const float dv = dinv[r * NN + v];
  const int c0 = roff + lane * 4;

  bf16x4 hs = *(const bf16x4*)&P[(size_t)v * 768 + c0];
  float a0 = (float)hs[0], a1 = (float)hs[1], a2 = (float)hs[2], a3 = (float)hs[3];

  int i = rpr[v];
  const int e = rpr[v + 1];
  for (; i + 16 <= e; i += 16) {
    bf16x4 h[16];
#pragma unroll
    for (int u = 0; u < 16; ++u) {
      int s = cr[i + u];
      h[u] = *(const bf16x4*)&P[(size_t)s * 768 + c0];
    }
#pragma unroll
    for (int u = 0; u < 16; ++u) {
      a0 += (float)h[u][0]; a1 += (float)h[u][1];
      a2 += (float)h[u][2]; a3 += (float)h[u][3];
    }
  }
  for (; i + 4 <= e; i += 4) {
    bf16x4 h[4];
#pragma unroll
    for (int u = 0; u < 4; ++u) {
      int s = cr[i + u];
      h[u] = *(const bf16x4*)&P[(size_t)s * 768 + c0];
    }
#pragma unroll
    for (int u = 0; u < 4; ++u) {
      a0 += (float)h[u][0]; a1 += (float)h[u][1];
      a2 += (float)h[u][2]; a3 += (float)h[u][3];
    }
  }
  for (; i < e; ++i) {
    int s = cr[i];
    bf16x4 h = *(const bf16x4*)&P[(size_t)s * 768 + c0];
    a0 += (float)h[0]; a1 += (float)h[1];
    a2 += (float)h[2]; a3 += (float)h[3];
  }
  f32x4 bb = ld4u(bias + c0);
  bf16x4 o;
  o[0] = (bf16_t)fmaxf(dv * a0 + bb[0], 0.f);
  o[1] = (bf16_t)fmaxf(dv * a1 + bb[1], 0.f);
  o[2] = (bf16_t)fmaxf(dv * a2 + bb[2], 0.f);
  o[3] = (bf16_t)fmaxf(dv * a3 + bb[3], 0.f);
  *(bf16x4*)&Out[(size_t)v * 768 + c0] = o;
}

// ---------------------------------------------------------------------------
// Readout: group means via index-CSR (no atomics) + MLP + log_softmax.
// ---------------------------------------------------------------------------
__global__ __launch_bounds__(256) void k_final2(
    const bf16_t* __restrict__ h2,
    const int* __restrict__ rpg, const int* __restrict__ colg,
    const float* __restrict__ mw1, const float* __restrict__ mb1,
    const float* __restrict__ mw2, const float* __restrict__ mb2,
    float* __restrict__ out)
{
  __shared__ float xc[768];
  __shared__ float tt[256];
  __shared__ float lg[8];
  const int g = blockIdx.x, tid = threadIdx.x;
  const int* rp1 = rpg;
  const int* rp3 = rpg + (NORIG + 1);
  const int* c1v = colg;
  const int* c3v = colg + NN;

  float a1 = 0.f;
  int b1 = rp1[g], e1 = rp1[g + 1];
  for (int i = b1; i < e1; ++i) a1 += (float)h2[(size_t)c1v[i] * 256 + tid];
  float a3 = 0.f;
  int b3 = rp3[g], e3 = rp3[g + 1];
  for (int i = b3; i < e3; ++i) a3 += (float)h2[(size_t)c3v[i] * 256 + tid];
  a1 *= 1.f / fmaxf((float)(e1 - b1), 1.f);
  a3 *= 1.f / fmaxf((float)(e3 - b3), 1.f);
  xc[tid] = a1;
  xc[256 + tid] = a3;
  xc[512 + tid] = a3;
  __syncthreads();
  float acc = mb1[tid];
  for (int k = 0; k < 768; ++k) acc += xc[k] * mw1[k * 256 + tid];
  tt[tid] = fmaxf(acc, 0.f);
  __syncthreads();
  if (tid < 7) {
    float a = mb2[tid];
    for (int k = 0; k < 256; ++k) a += tt[k] * mw2[k * 7 + tid];
    lg[tid] = a;
  }
  __syncthreads();
  if (tid == 0) {
    float mx = lg[0];
    for (int c2 = 1; c2 < 7; ++c2) mx = fmaxf(mx, lg[c2]);
    float sum = 0.f;
    for (int c2 = 0; c2 < 7; ++c2) sum += expf(lg[c2] - mx);
    float lse = logf(sum) + mx;
    for (int c2 = 0; c2 < 7; ++c2) out[g * 7 + c2] = lg[c2] - lse;
  }
}

// ---------------------------------------------------------------------------
extern "C" void kernel_launch(void* const* d_in, const int* in_sizes, int n_in,
                              void* d_out, int out_size, void* d_ws, size_t ws_size,
                              hipStream_t stream) {
  const float* x    = (const float*)d_in[0];
  const float* w1   = (const float*)d_in[1];
  const float* b1   = (const float*)d_in[2];
  const float* w2   = (const float*)d_in[3];
  const float* b2   = (const float*)d_in[4];
  const float* m1w1 = (const float*)d_in[5];
  const float* m1b1 = (const float*)d_in[6];
  const float* m1w2 = (const float*)d_in[7];
  const float* m1b2 = (const float*)d_in[8];
  const float* m2w1 = (const float*)d_in[9];
  const float* m2b1 = (const float*)d_in[10];
  const float* m2w2 = (const float*)d_in[11];
  const float* m2b2 = (const float*)d_in[12];
  const float* mw1  = (const float*)d_in[13];
  const float* mb1  = (const float*)d_in[14];
  const float* mw2  = (const float*)d_in[15];
  const float* mb2  = (const float*)d_in[16];
  const int* e1 = (const int*)d_in[17];
  const int* e2 = (const int*)d_in[18];
  const int* e3 = (const int*)d_in[19];
  const int* i1 = (const int*)d_in[20];
  const int* i3 = (const int*)d_in[22];  // index_2 dead in reference (source bug)
  float* out = (float*)d_out;

  char* ws = (char*)d_ws;
  size_t off = 0;
  auto alloc = [&](size_t bytes) {
    char* p = ws + off;
    off += (bytes + 255) & ~(size_t)255;
    return (void*)p;
  };
  bf16_t* xb     = (bf16_t*)alloc((size_t)NN * KP1 * 2);   // 208.6 MB
  bf16_t* wt     = (bf16_t*)alloc((size_t)768 * KP1 * 2);  // w1^T, 8 MB
  bf16_t* d_m1w1 = (bf16_t*)alloc((size_t)256 * 768 * 2);
  bf16_t* d_m1w2 = (bf16_t*)alloc((size_t)256 * 256 * 2);
  bf16_t* d_w2   = (bf16_t*)alloc((size_t)768 * 256 * 2);
  bf16_t* d_m2w1 = (bf16_t*)alloc((size_t)256 * 768 * 2);
  bf16_t* d_m2w2 = (bf16_t*)alloc((size_t)256 * 256 * 2);
  bf16_t* a1     = (bf16_t*)alloc((size_t)NN * 768 * 2);
  bf16_t* g1     = (bf16_t*)alloc((size_t)NN * 768 * 2);
  bf16_t* t1     = (bf16_t*)alloc((size_t)NN * 256 * 2);
  bf16_t* h1     = (bf16_t*)alloc((size_t)NN * 256 * 2);
  int*    deg    = (int*)alloc(((size_t)3 * NN + 2 * NORIG) * 4);
  float*  dinv   = (float*)alloc((size_t)3 * NN * 4);
  int*    rp     = (int*)alloc((size_t)3 * (NN + 1) * 4);
  int*    cur    = (int*)alloc((size_t)3 * NN * 4);
  int*    col    = (int*)alloc((size_t)3 * NE * 4);
  int*    rpg    = (int*)alloc((size_t)2 * (NORIG + 1) * 4);
  int*    cur183 = (int*)alloc((size_t)2 * NORIG * 4);
  int*    colg   = (int*)alloc((size_t)2 * NN * 4);
  int*    deg183 = deg + 3 * NN;

  // ---- CSR build (merged) + dinv
  hipMemsetAsync(deg, 0, ((size_t)3 * NN + 2 * NORIG) * 4, stream);
  const int gall = (3 * NE + 2 * NN + 255) / 256;
  k_degall<<<gall, 256, 0, stream>>>(e1, e2, e3, i1, i3, deg, deg183);
  k_scanall<<<5, SCAN_T, 0, stream>>>(deg, deg183, rp, cur, rpg, cur183, dinv);
  k_bucketall<<<gall, 256, 0, stream>>>(e1, e2, e3, i1, i3, cur, col, cur183, colg);

  // ---- all weight transposes up front (2 launches)
  k_transw<<<dim3(KP1 / 32, 8, 3), dim3(32, 8), 0, stream>>>(w1, wt, FIN, KP1);
  k_transw5<<<dim3(24, 8, 7), dim3(32, 8), 0, stream>>>(
      m1w1, m1w2, w2, m2w1, m2w2, d_m1w1, d_m1w2, d_w2, d_m2w1, d_m2w2);

  k_cvtpad<<<2048, 256, 0, stream>>>(x, xb);

  dim3 ggat(NN / 4, 3);
  const int NWGW = 3 * 157;

  // ---- layer 1 (GEMM writes pre-scaled P = H*dinv for the gather)
  k_gemm_w<<<NWGW, 512, 0, stream>>>(xb, wt, a1, nullptr, dinv, NN, 768, KP1, 0, 3);
  k_gatherb<<<ggat, 256, 0, stream>>>(a1, g1, rp, col, dinv, b1);
  k_gemm_s<<<dim3(2, 157), 256, 0, stream>>>(g1, d_m1w1, t1, m1b1, NN, 256, 768, 1);
  k_gemm_s<<<dim3(2, 157), 256, 0, stream>>>(t1, d_m1w2, h1, m1b2, NN, 256, 256, 0);

  // ---- layer 2
  k_gemm_w<<<NWGW, 512, 0, stream>>>(h1, d_w2, a1, nullptr, dinv, NN, 768, 256, 0, 3);
  k_gatherb<<<ggat, 256, 0, stream>>>(a1, g1, rp, col, dinv, b2);
  k_gemm_s<<<dim3(2, 157), 256, 0, stream>>>(g1, d_m2w1, t1, m2b1, NN, 256, 768, 1);
  k_gemm_s<<<dim3(2, 157), 256, 0, stream>>>(t1, d_m2w2, h1, m2b2, NN, 256, 256, 0);

  // ---- readout (atomic-free)
  k_final2<<<NORIG, 256, 0, stream>>>(h1, rpg, colg, mw1, mb1, mw2, mb2, out);
}